// Round 16
// baseline (236.595 us; speedup 1.0000x reference)
//
#include <hip/hip_runtime.h>
#include <hip/hip_bf16.h>

typedef __attribute__((ext_vector_type(8))) short short8;
typedef __attribute__((ext_vector_type(4))) short short4v;
typedef __attribute__((ext_vector_type(4))) float f32x4;
typedef __attribute__((ext_vector_type(2))) float f32x2;

__device__ __forceinline__ unsigned short f2bf(float f) {
    unsigned int u = __builtin_bit_cast(unsigned int, f);
    u += 0x7fffu + ((u >> 16) & 1u);   // round-to-nearest-even
    return (unsigned short)(u >> 16);
}
__device__ __forceinline__ unsigned int pack2(float a, float b) {
    union { __hip_bfloat162 h; unsigned int u; } r;
    r.h = __float22bfloat162_rn(make_float2(a, b));
    return r.u;
}
__device__ __forceinline__ short4v cvt4(float a, float b, float c, float d) {
    union { __hip_bfloat162 h[2]; short4v s; } u;
    u.h[0] = __float22bfloat162_rn(make_float2(a, b));
    u.h[1] = __float22bfloat162_rn(make_float2(c, d));
    return u.s;
}

// ---------------------------------------------------------------------------
// Kernel A: partial adjacency sums over 60-frame chunks. grid (5,32).
// ---------------------------------------------------------------------------
__global__ void kA(const float* __restrict__ xx, float* __restrict__ At_part) {
    __shared__ float xs3[3][60][25];
    const int tc = blockIdx.x, n = blockIdx.y;
    const int tid = threadIdx.x;
    const float* base = xx + (size_t)n * 22500 + tc * 1500;
    for (int idx = tid; idx < 4500; idx += 256) {
        int ch = idx / 1500, rt = idx % 1500;
        xs3[ch][rt / 25][rt % 25] = base[ch * 7500 + rt];
    }
    __syncthreads();
    for (int p = tid; p < 625; p += 256) {
        int v = p / 25, u = p % 25;
        float s = 0.f;
        for (int t = 0; t < 60; ++t) {
            float dx = xs3[0][t][v] - xs3[0][t][u];
            float dy = xs3[1][t][v] - xs3[1][t][u];
            float dz = xs3[2][t][v] - xs3[2][t][u];
            s += __expf(-2.f * (dx * dx + dy * dy + dz * dz));
        }
        At_part[(size_t)(n * 5 + tc) * 625 + p] = s;
    }
}

// ---------------------------------------------------------------------------
// Kernel B1: per-sample reduce + symmetric normalization. grid 32.
// ---------------------------------------------------------------------------
__global__ void kB1(const float* __restrict__ At_part, float* __restrict__ Acontrib) {
    __shared__ float At[625];
    __shared__ float dinv[25];
    const int n = blockIdx.x, tid = threadIdx.x;
    for (int p = tid; p < 625; p += 256) {
        float s = 0.f;
        for (int tc = 0; tc < 5; ++tc) s += At_part[(size_t)(n * 5 + tc) * 625 + p];
        At[p] = s;
    }
    __syncthreads();
    if (tid < 25) {
        float d = 0.f;
        for (int u = 0; u < 25; ++u) d += At[tid * 25 + u];
        dinv[tid] = rsqrtf(d * (1.f / 300.f));
    }
    __syncthreads();
    for (int p = tid; p < 625; p += 256)
        Acontrib[n * 625 + p] = At[p] * (1.f / 300.f) * dinv[p / 25] * dinv[p % 25] * (1.f / 32.f);
}

// ---------------------------------------------------------------------------
// Kernel B2: block 0 -> bsTg (bf16 [64][72], zero-padded) + fused bias;
//            blocks 1..36 -> W'' = W * bn_scale  (layout [o][k], row-major).
// ---------------------------------------------------------------------------
__global__ void kB2(const float* __restrict__ Acontrib, const float* __restrict__ A_res,
                    const float* __restrict__ W, const float* __restrict__ b,
                    const float* __restrict__ gamma, const float* __restrict__ beta,
                    const float* __restrict__ rm, const float* __restrict__ rv,
                    short* __restrict__ bsTg, short* __restrict__ Wpg,
                    float* __restrict__ bbg) {
    const int tid = threadIdx.x;
    if (blockIdx.x == 0) {
        __shared__ float macc[625];
        for (int p = tid; p < 625; p += 256) {
            float s = 0.f;
            for (int n = 0; n < 32; ++n) s += Acontrib[n * 625 + p];
            macc[p] = s;
        }
        __syncthreads();
        for (int idx = tid; idx < 64 * 72; idx += 256) {
            int col = idx / 72, u = idx % 72;
            float v = 0.f;
            if (col < 50 && u < 50) v = macc[(col % 25) * 25 + (u % 25)] + A_res[col * 50 + u];
            bsTg[idx] = (short)f2bf(v);
        }
        if (tid < 192) {
            float sc = gamma[tid] * rsqrtf(rv[tid] + 1e-5f);
            bbg[tid] = b[tid] * sc + beta[tid] - rm[tid] * sc;
        }
    } else {
        const int e = (blockIdx.x - 1) * 1024 + tid * 4;
        const int o = e / 192;
        const float sc = gamma[o] * rsqrtf(rv[o] + 1e-5f);
        float4 w = *(const float4*)(W + e);
        short4v s4 = { (short)f2bf(w.x * sc), (short)f2bf(w.y * sc),
                       (short)f2bf(w.z * sc), (short)f2bf(w.w * sc) };
        *(short4v*)(Wpg + e) = s4;
    }
}

// ---------------------------------------------------------------------------
// Kernel B2b: W'' in MFMA-fragment order for kC2's coalesced wf loads.
// ---------------------------------------------------------------------------
__global__ void kB2b(const float* __restrict__ W, const float* __restrict__ gamma,
                     const float* __restrict__ rv, short* __restrict__ Wfrag) {
    const int idx = blockIdx.x * 256 + threadIdx.x;     // < 4608
    const int ot = idx / 384, r = idx - ot * 384;
    const int ks = r / 64, lane = r - ks * 64;
    const int o = ot * 16 + (lane & 15);
    const int k0 = ks * 32 + (lane >> 4) * 8;
    const float sc = gamma[o] * rsqrtf(rv[o] + 1e-5f);
    float4 w0 = *(const float4*)(W + o * 192 + k0);
    float4 w1 = *(const float4*)(W + o * 192 + k0 + 4);
    union { short4v h[2]; short8 v; } u;
    u.h[0] = cvt4(w0.x * sc, w0.y * sc, w0.z * sc, w0.w * sc);
    u.h[1] = cvt4(w1.x * sc, w1.y * sc, w1.z * sc, w1.w * sc);
    *(short8*)(Wfrag + (size_t)idx * 8) = u.v;
}

// ---------------------------------------------------------------------------
// PATH A kernel 1: GEMM1 -> agg2 in MFMA-FRAGMENT order:
//   agg2[((n*300+t)*6 + wid)*1024 + lane*16 + j]  (j = m*4+r, bf16, v-pad incl)
// Each lane stores 2x16B at lane*32 -> wave-contiguous 1KB stores (no a2T
// LDS transpose, no dump, ONE lgkm+barrier per t).  grid (30,32), 384 thr.
// ---------------------------------------------------------------------------
#define TC1 10
__global__ __launch_bounds__(384, 3)
void kC1(const float* __restrict__ x, const short* __restrict__ bsTg,
         short* __restrict__ agg2) {
    __shared__ __align__(16) char xsb[2 * 12288];   // 2 one-timestep slots

    const int tid = threadIdx.x;
    const int lane = tid & 63;
    const int wid = tid >> 6;          // 0..5
    const int lam = lane & 15;
    const int kc = (lane >> 4) * 8;
    const int n = blockIdx.y;
    const int t0 = blockIdx.x * TC1;
    const int gb0 = n * 1440000 + t0 * 50;
    const int cgl = wid * 16 + lam;

    // A_scale fragments in registers (identical across waves)
    short8 af[2][4];
#pragma unroll
    for (int ks = 0; ks < 2; ++ks)
#pragma unroll
        for (int m = 0; m < 4; ++m)
            af[ks][m] = *(const short8*)(bsTg + (m * 16 + lam) * 72 + ks * 32 + kc);

    // t-invariant per-thread stage offsets (coalesced: lane-consecutive q)
    int goff[7], loff[7];
#pragma unroll
    for (int i = 0; i < 7; ++i) {
        int idx = i * 384 + tid;
        int idc = idx < 2400 ? idx : 2399;
        int c = idc / 25, q = idc - c * 25;
        goff[i] = c * 15000 + 2 * q;
        loff[i] = (c * 128 + q * 4) ^ ((c & 7) << 4);
    }

    // zero u=50..63 pads (both slots)
    for (int idx = tid; idx < 1344; idx += 384) {
        int r = idx / 7, k = idx - r * 7;
        int slot = r / 96, c = r - 96 * slot;
        *(unsigned int*)(xsb + ((slot * 12288 + c * 128 + (50 + 2 * k) * 2) ^ ((c & 7) << 4))) = 0;
    }

    // prologue: stage t0 -> slot0, t1 -> slot1
    f32x2 pf2[13];
#pragma unroll
    for (int i = 0; i < 13; ++i) {
        int idx = i * 384 + tid;
        idx = idx < 4800 ? idx : 4799;
        int c = idx / 50, q2 = idx - c * 50;
        int tl = q2 >= 25, q = q2 - 25 * tl;
        pf2[i] = *(const f32x2*)(x + gb0 + c * 15000 + tl * 50 + 2 * q);
    }
#pragma unroll
    for (int i = 0; i < 13; ++i) {
        int idx = i * 384 + tid;
        if (idx < 4800) {
            int c = idx / 50, q2 = idx - c * 50;
            int tl = q2 >= 25, q = q2 - 25 * tl;
            *(unsigned int*)(xsb + ((tl * 12288 + c * 128 + q * 4) ^ ((c & 7) << 4)))
                = pack2(pf2[i].x, pf2[i].y);
        }
    }
    asm volatile("s_waitcnt lgkmcnt(0)" ::: "memory");
    __builtin_amdgcn_s_barrier();

    const f32x4 z = {0.f, 0.f, 0.f, 0.f};
    f32x2 pf[7];
    short* aout = agg2 + (((size_t)(n * 300 + t0) * 6 + wid) << 10) + (lane << 4);

#pragma unroll 1
    for (int tl = 0; tl < TC1; ++tl) {
        const int slot = tl & 1;

        // 1. issue t+2 coalesced loads early
        if (tl < TC1 - 2) {
            const float* xb2 = x + gb0 + (tl + 2) * 50;
#pragma unroll
            for (int i = 0; i < 7; ++i)
                if (i < 6 || tid < 96) pf[i] = *(const f32x2*)(xb2 + goff[i]);
        }

        // 2. read this wave's x fragments from slot
        short8 xb[2];
#pragma unroll
        for (int ks = 0; ks < 2; ++ks)
            xb[ks] = *(const short8*)(xsb +
                ((slot * 12288 + cgl * 128 + (ks * 32 + kc) * 2) ^ ((cgl & 7) << 4)));

        // 3. all waves done reading slot -> writers may overwrite after barrier
        asm volatile("s_waitcnt lgkmcnt(0)" ::: "memory");
        __builtin_amdgcn_s_barrier();

        // 4. GEMM1: D[v][c] (8 MFMA), then wave-contiguous fragment stores
        f32x4 acc1[4];
#pragma unroll
        for (int m = 0; m < 4; ++m) acc1[m] = z;
#pragma unroll
        for (int ks = 0; ks < 2; ++ks)
#pragma unroll
            for (int m = 0; m < 4; ++m)
                acc1[m] = __builtin_amdgcn_mfma_f32_16x16x32_bf16(af[ks][m], xb[ks], acc1[m], 0, 0, 0);

        union { short4v h[2]; short8 v; } s0, s1;
        s0.h[0] = cvt4(acc1[0][0], acc1[0][1], acc1[0][2], acc1[0][3]);
        s0.h[1] = cvt4(acc1[1][0], acc1[1][1], acc1[1][2], acc1[1][3]);
        s1.h[0] = cvt4(acc1[2][0], acc1[2][1], acc1[2][2], acc1[2][3]);
        s1.h[1] = cvt4(acc1[3][0], acc1[3][1], acc1[3][2], acc1[3][3]);
        short* ap = aout + tl * 6144;
        *(short8*)(ap) = s0.v;
        *(short8*)(ap + 8) = s1.v;

        // 5. write t+2 into the freed slot (visible after next lgkm+barrier)
        if (tl < TC1 - 2) {
            char* xw = xsb + slot * 12288;
#pragma unroll
            for (int i = 0; i < 7; ++i)
                if (i < 6 || tid < 96)
                    *(unsigned int*)(xw + loff[i]) = pack2(pf[i].x, pf[i].y);
        }
    }
}

// ---------------------------------------------------------------------------
// PATH A kernel 2: out = ReLU(W'' @ agg2 + bias).  grid (150,32) x 256 thr.
// Tile = (n, 2 timesteps).  Fill reads the fragment layout FULLY CONTIGUOUS
// (24.6 KB/block) and performs the (v,c)->asb transpose into banked LDS.
// GEMM2 + stores = proven R12 structure (200-short rows, 2-way banks).
// ---------------------------------------------------------------------------
__global__ __launch_bounds__(256, 3)
void kC2(const short* __restrict__ agg2, const short* __restrict__ Wfrag,
         const float* __restrict__ bbg, float* __restrict__ out) {
    __shared__ __align__(16) short asb[64][200];    // 25600 B

    const int tid = threadIdx.x;
    const int lane = tid & 63;
    const int wid = tid >> 6;          // 0..3
    const int lam = lane & 15;
    const int kc = (lane >> 4) * 8;
    const int cb = (lane >> 4) * 4;
    const int n = blockIdx.y;
    const int bx = blockIdx.x;         // t = 2bx, 2bx+1

    // W'' fragments (coalesced) + bias
    short8 wf[3][6];
    float bb[3];
#pragma unroll
    for (int j = 0; j < 3; ++j) {
        const int ot = wid * 3 + j;
#pragma unroll
        for (int ks = 0; ks < 6; ++ks)
            wf[j][ks] = *(const short8*)(Wfrag + ((size_t)(ot * 6 + ks) * 64 + lane) * 8);
        bb[j] = bbg[ot * 16 + lam];
    }

    // fill + transpose: fragment dwords -> asb[tl*25+vs][s*96+c]
    {
        const unsigned int* src = (const unsigned int*)agg2
            + (size_t)(n * 300 + 2 * bx) * 3072;
#pragma unroll
        for (int k = 0; k < 24; ++k) {
            int i = k * 256 + tid;                  // 0..6143
            unsigned int w = src[i];
            int tl = i >= 3072;
            int d = i - tl * 3072;
            int wid_s = d >> 9, rem = d & 511;
            int lane_s = rem >> 3, dj = rem & 7;
            int c = (wid_s << 4) + (lane_s & 15);
            int v0 = ((dj >> 1) << 4) + ((lane_s >> 4) << 2) + ((dj & 1) << 1);
            if (v0 < 50) {                          // v0 even; v0,v0+1 valid together
                int s0 = v0 >= 25;
                asb[tl * 25 + v0 - 25 * s0][s0 * 96 + c] = (short)(w & 0xffffu);
                int v1 = v0 + 1;
                int s1 = v1 >= 25;
                asb[tl * 25 + v1 - 25 * s1][s1 * 96 + c] = (short)(w >> 16);
            }
        }
    }
    __syncthreads();

    const f32x4 z = {0.f, 0.f, 0.f, 0.f};
    f32x4 acc[4][3];
#pragma unroll
    for (int m = 0; m < 4; ++m)
#pragma unroll
        for (int j = 0; j < 3; ++j) acc[m][j] = z;

#pragma unroll
    for (int ks = 0; ks < 6; ++ks) {
        short8 a[4];
#pragma unroll
        for (int m = 0; m < 4; ++m)
            a[m] = *(const short8*)(&asb[m * 16 + lam][ks * 32 + kc]);
#pragma unroll
        for (int m = 0; m < 4; ++m)
#pragma unroll
            for (int j = 0; j < 3; ++j)
                acc[m][j] = __builtin_amdgcn_mfma_f32_16x16x32_bf16(a[m], wf[j][ks], acc[m][j], 0, 0, 0);
    }

    // stores: row = m*16+cb+r in [0,50); out offset = (n*192+o)*7500 + bx*50 + row
#pragma unroll
    for (int m = 0; m < 4; ++m) {
        const int tvb = m * 16 + cb;
        if (tvb < 50) {
#pragma unroll
            for (int j = 0; j < 3; ++j) {
                const int o = (wid * 3 + j) * 16 + lam;
                float* op = out + (size_t)(n * 192 + o) * 7500 + bx * 50 + tvb;
                float v0 = acc[m][j][0] + bb[j]; v0 = v0 > 0.f ? v0 : 0.f;
                float v1 = acc[m][j][1] + bb[j]; v1 = v1 > 0.f ? v1 : 0.f;
                f32x2 p0 = {v0, v1};
                *(f32x2*)op = p0;
                if (tvb < 48) {                     // rows 48,49 tail has only 2 valid
                    float v2 = acc[m][j][2] + bb[j]; v2 = v2 > 0.f ? v2 : 0.f;
                    float v3 = acc[m][j][3] + bb[j]; v3 = v3 > 0.f ? v3 : 0.f;
                    f32x2 p1 = {v2, v3};
                    *(f32x2*)(op + 2) = p1;
                }
            }
        }
    }
}

// ---------------------------------------------------------------------------
// PATH B fallback (== R11 fused kernel), used when ws is too small.
// ---------------------------------------------------------------------------
__device__ __forceinline__ void ldx_fb(const float* __restrict__ x, int gbase,
                                       f32x2 (&pf)[7], int tid) {
#pragma unroll
    for (int i = 0; i < 7; ++i) {
        int idx = i * 384 + tid;
        idx = idx < 2400 ? idx : 2399;
        int c = idx / 25, q = idx - c * 25;
        pf[i] = *(const f32x2*)(x + gbase + c * 15000 + 2 * q);
    }
}
__device__ __forceinline__ void stx_fb(char* xsb, int slot, const f32x2 (&pf)[7], int tid) {
#pragma unroll
    for (int i = 0; i < 7; ++i) {
        int idx = i * 384 + tid;
        if (idx < 2400) {
            int c = idx / 25, q = idx - c * 25;
            *(unsigned int*)(xsb + ((slot * 12288 + c * 128 + q * 4) ^ ((c & 7) << 4)))
                = pack2(pf[i].x, pf[i].y);
        }
    }
}

__global__ __launch_bounds__(384, 3)
void kC(const float* __restrict__ x, const short* __restrict__ Wpg,
        const short* __restrict__ bsTg, const float* __restrict__ bbg,
        float* __restrict__ out) {
    __shared__ __align__(16) char xsb[2 * 12288];
    __shared__ __align__(16) short bsT[64 * 72];
    __shared__ __align__(16) short a2T[2][32][208];

    const int tid = threadIdx.x;
    const int lane = tid & 63;
    const int wid = tid >> 6;
    const int lam = lane & 15;
    const int kc = (lane >> 4) * 8;
    const int cb = (lane >> 4) * 4;
    const int n = blockIdx.y;
    const int t0 = blockIdx.x * 4;
    const int gb0 = n * 1440000 + t0 * 50;
    const int cgl = wid * 16 + lam;

    f32x2 pf2[13];
#pragma unroll
    for (int i = 0; i < 13; ++i) {
        int idx = i * 384 + tid;
        idx = idx < 4800 ? idx : 4799;
        int c = idx / 50, q2 = idx - c * 50;
        int tl = q2 >= 25, q = q2 - 25 * tl;
        pf2[i] = *(const f32x2*)(x + gb0 + c * 15000 + tl * 50 + 2 * q);
    }
    short8 wf[2][6];
#pragma unroll
    for (int ot = 0; ot < 2; ++ot)
#pragma unroll
        for (int ks = 0; ks < 6; ++ks)
            wf[ot][ks] = *(const short8*)(Wpg + ((2 * wid + ot) * 16 + lam) * 192 + ks * 32 + kc);
    float bb[2];
#pragma unroll
    for (int ot = 0; ot < 2; ++ot) bb[ot] = bbg[(2 * wid + ot) * 16 + lam];
    {
        const int4* src = (const int4*)bsTg;
        int4* dst = (int4*)bsT;
        for (int i = tid; i < 576; i += 384) dst[i] = src[i];
    }
    for (int idx = tid; idx < 1344; idx += 384) {
        int r = idx / 7, k = idx - r * 7;
        int slot = r / 96, c = r - 96 * slot;
        *(unsigned int*)(xsb + ((slot * 12288 + c * 128 + (50 + 2 * k) * 2) ^ ((c & 7) << 4))) = 0;
    }
    for (int idx = tid; idx < 1456; idx += 384) {
        int buf = idx / 728, rem = idx - buf * 728;
        int row = 25 + rem / 104, col2 = rem - (rem / 104) * 104;
        *((unsigned int*)&a2T[buf][row][0] + col2) = 0;
    }
#pragma unroll
    for (int i = 0; i < 13; ++i) {
        int idx = i * 384 + tid;
        if (idx < 4800) {
            int c = idx / 50, q2 = idx - c * 50;
            int tl = q2 >= 25, q = q2 - 25 * tl;
            *(unsigned int*)(xsb + ((tl * 12288 + c * 128 + q * 4) ^ ((c & 7) << 4)))
                = pack2(pf2[i].x, pf2[i].y);
        }
    }
    asm volatile("s_waitcnt lgkmcnt(0)" ::: "memory");
    __builtin_amdgcn_s_barrier();

    const f32x4 z = {0.f, 0.f, 0.f, 0.f};
    f32x2 pf[7];

#pragma unroll 1
    for (int tl = 0; tl < 4; ++tl) {
        const int slot = tl & 1;
        short* a2w = &a2T[slot][0][0];
        if (tl < 2) ldx_fb(x, gb0 + (tl + 2) * 50, pf, tid);

        short8 xb[2];
#pragma unroll
        for (int ks = 0; ks < 2; ++ks)
            xb[ks] = *(const short8*)(xsb +
                ((slot * 12288 + cgl * 128 + (ks * 32 + kc) * 2) ^ ((cgl & 7) << 4)));
        f32x4 acc1[4];
#pragma unroll
        for (int m = 0; m < 4; ++m) acc1[m] = z;
#pragma unroll
        for (int ks = 0; ks < 2; ++ks)
#pragma unroll
            for (int m = 0; m < 4; ++m) {
                const short8 af = *(const short8*)(bsT + (m * 16 + lam) * 72 + ks * 32 + kc);
                acc1[m] = __builtin_amdgcn_mfma_f32_16x16x32_bf16(af, xb[ks], acc1[m], 0, 0, 0);
            }
#pragma unroll
        for (int m = 0; m < 3; ++m) {
            short4v sv = cvt4(acc1[m][0], acc1[m][1], acc1[m][2], acc1[m][3]);
#pragma unroll
            for (int r = 0; r < 4; ++r) {
                const int v = m * 16 + cb + r;
                const int s = v >= 25;
                a2w[(v - 25 * s) * 208 + s * 96 + cgl] = sv[r];
            }
        }
        if (cb == 0) {
            a2w[23 * 208 + 96 + cgl] = (short)f2bf(acc1[3][0]);
            a2w[24 * 208 + 96 + cgl] = (short)f2bf(acc1[3][1]);
        }
        asm volatile("s_waitcnt lgkmcnt(0)" ::: "memory");
        __builtin_amdgcn_s_barrier();

        f32x4 acc2[2][2];
#pragma unroll
        for (int g = 0; g < 2; ++g) { acc2[g][0] = z; acc2[g][1] = z; }
#pragma unroll
        for (int ks = 0; ks < 6; ++ks) {
            const short8 A0 = *(const short8*)(a2w + lam * 208 + ks * 32 + kc);
            const short8 A1 = *(const short8*)(a2w + (16 + lam) * 208 + ks * 32 + kc);
#pragma unroll
            for (int ot = 0; ot < 2; ++ot) {
                acc2[0][ot] = __builtin_amdgcn_mfma_f32_16x16x32_bf16(A0, wf[ot][ks], acc2[0][ot], 0, 0, 0);
                acc2[1][ot] = __builtin_amdgcn_mfma_f32_16x16x32_bf16(A1, wf[ot][ks], acc2[1][ot], 0, 0, 0);
            }
        }
        if (tl < 2) stx_fb(xsb, slot, pf, tid);

        const int t = t0 + tl;
#pragma unroll
        for (int ot = 0; ot < 2; ++ot) {
            const int o = (2 * wid + ot) * 16 + lam;
            float* op = out + ((size_t)(n * 192 + o) * 300 + t) * 25;
#pragma unroll
            for (int r = 0; r < 4; ++r) {
                float vv = acc2[0][ot][r] + bb[ot];
                op[cb + r] = vv > 0.f ? vv : 0.f;
            }
#pragma unroll
            for (int r = 0; r < 4; ++r) {
                const int tv = 16 + cb + r;
                if (tv < 25) {
                    float vv = acc2[1][ot][r] + bb[ot];
                    op[tv] = vv > 0.f ? vv : 0.f;
                }
            }
        }
    }
}

// ---------------------------------------------------------------------------
extern "C" void kernel_launch(void* const* d_in, const int* in_sizes, int n_in,
                              void* d_out, int out_size, void* d_ws, size_t ws_size,
                              hipStream_t stream) {
    const float* x     = (const float*)d_in[0];
    const float* xx    = (const float*)d_in[1];
    const float* A_res = (const float*)d_in[2];
    const float* W     = (const float*)d_in[3];
    const float* b     = (const float*)d_in[4];
    const float* gamma = (const float*)d_in[5];
    const float* beta  = (const float*)d_in[6];
    const float* rm    = (const float*)d_in[7];
    const float* rv    = (const float*)d_in[8];
    float* out = (float*)d_out;

    char* ws = (char*)d_ws;
    float* At_part  = (float*)ws;                    // 400000 B
    float* Acontrib = (float*)(ws + 400000);         //  80000 B
    short* bsTg     = (short*)(ws + 480000);         //   9216 B
    short* Wpg      = (short*)(ws + 489216);         //  73728 B
    float* bbg      = (float*)(ws + 562944);         //    768 B
    short* Wfrag    = (short*)(ws + 563712);         //  73728 B -> ends 637440
    short* agg2     = (short*)(ws + 637440);         // 117964800 B (PATH A only)
    const bool bigws = ws_size >= (size_t)637440 + 117964800u;

    kA<<<dim3(5, 32), 256, 0, stream>>>(xx, At_part);
    kB1<<<32, 256, 0, stream>>>(At_part, Acontrib);
    kB2<<<37, 256, 0, stream>>>(Acontrib, A_res, W, b, gamma, beta, rm, rv, bsTg, Wpg, bbg);
    kB2b<<<18, 256, 0, stream>>>(W, gamma, rv, Wfrag);

    if (bigws) {
        kC1<<<dim3(30, 32), 384, 0, stream>>>(x, bsTg, agg2);
        kC2<<<dim3(150, 32), 256, 0, stream>>>(agg2, Wfrag, bbg, out);
    } else {
        kC<<<dim3(75, 32), 384, 0, stream>>>(x, Wpg, bsTg, bbg, out);
    }
}

// Round 17
// 231.249 us; speedup vs baseline: 1.0231x; 1.0231x over previous
//
#include <hip/hip_runtime.h>
#include <hip/hip_bf16.h>

typedef __attribute__((ext_vector_type(8))) short short8;
typedef __attribute__((ext_vector_type(4))) short short4v;
typedef __attribute__((ext_vector_type(4))) float f32x4;
typedef __attribute__((ext_vector_type(2))) float f32x2;
typedef __attribute__((ext_vector_type(4))) unsigned int u32x4;

__device__ __forceinline__ unsigned short f2bf(float f) {
    unsigned int u = __builtin_bit_cast(unsigned int, f);
    u += 0x7fffu + ((u >> 16) & 1u);   // round-to-nearest-even
    return (unsigned short)(u >> 16);
}
__device__ __forceinline__ unsigned int pack2(float a, float b) {
    union { __hip_bfloat162 h; unsigned int u; } r;
    r.h = __float22bfloat162_rn(make_float2(a, b));
    return r.u;
}
__device__ __forceinline__ short4v cvt4(float a, float b, float c, float d) {
    union { __hip_bfloat162 h[2]; short4v s; } u;
    u.h[0] = __float22bfloat162_rn(make_float2(a, b));
    u.h[1] = __float22bfloat162_rn(make_float2(c, d));
    return u.s;
}

// ---------------------------------------------------------------------------
// Kernel A: partial adjacency sums over 60-frame chunks. grid (5,32).
// ---------------------------------------------------------------------------
__global__ void kA(const float* __restrict__ xx, float* __restrict__ At_part) {
    __shared__ float xs3[3][60][25];
    const int tc = blockIdx.x, n = blockIdx.y;
    const int tid = threadIdx.x;
    const float* base = xx + (size_t)n * 22500 + tc * 1500;
    for (int idx = tid; idx < 4500; idx += 256) {
        int ch = idx / 1500, rt = idx % 1500;
        xs3[ch][rt / 25][rt % 25] = base[ch * 7500 + rt];
    }
    __syncthreads();
    for (int p = tid; p < 625; p += 256) {
        int v = p / 25, u = p % 25;
        float s = 0.f;
        for (int t = 0; t < 60; ++t) {
            float dx = xs3[0][t][v] - xs3[0][t][u];
            float dy = xs3[1][t][v] - xs3[1][t][u];
            float dz = xs3[2][t][v] - xs3[2][t][u];
            s += __expf(-2.f * (dx * dx + dy * dy + dz * dz));
        }
        At_part[(size_t)(n * 5 + tc) * 625 + p] = s;
    }
}

// ---------------------------------------------------------------------------
// Kernel B1: per-sample reduce + symmetric normalization. grid 32.
// ---------------------------------------------------------------------------
__global__ void kB1(const float* __restrict__ At_part, float* __restrict__ Acontrib) {
    __shared__ float At[625];
    __shared__ float dinv[25];
    const int n = blockIdx.x, tid = threadIdx.x;
    for (int p = tid; p < 625; p += 256) {
        float s = 0.f;
        for (int tc = 0; tc < 5; ++tc) s += At_part[(size_t)(n * 5 + tc) * 625 + p];
        At[p] = s;
    }
    __syncthreads();
    if (tid < 25) {
        float d = 0.f;
        for (int u = 0; u < 25; ++u) d += At[tid * 25 + u];
        dinv[tid] = rsqrtf(d * (1.f / 300.f));
    }
    __syncthreads();
    for (int p = tid; p < 625; p += 256)
        Acontrib[n * 625 + p] = At[p] * (1.f / 300.f) * dinv[p / 25] * dinv[p % 25] * (1.f / 32.f);
}

// ---------------------------------------------------------------------------
// Kernel B2: block 0 -> bsTg (bf16 [64][72], zero-padded) + fused bias;
//            blocks 1..36 -> W'' = W * bn_scale  (layout [o][k], row-major).
// ---------------------------------------------------------------------------
__global__ void kB2(const float* __restrict__ Acontrib, const float* __restrict__ A_res,
                    const float* __restrict__ W, const float* __restrict__ b,
                    const float* __restrict__ gamma, const float* __restrict__ beta,
                    const float* __restrict__ rm, const float* __restrict__ rv,
                    short* __restrict__ bsTg, short* __restrict__ Wpg,
                    float* __restrict__ bbg) {
    const int tid = threadIdx.x;
    if (blockIdx.x == 0) {
        __shared__ float macc[625];
        for (int p = tid; p < 625; p += 256) {
            float s = 0.f;
            for (int n = 0; n < 32; ++n) s += Acontrib[n * 625 + p];
            macc[p] = s;
        }
        __syncthreads();
        for (int idx = tid; idx < 64 * 72; idx += 256) {
            int col = idx / 72, u = idx % 72;
            float v = 0.f;
            if (col < 50 && u < 50) v = macc[(col % 25) * 25 + (u % 25)] + A_res[col * 50 + u];
            bsTg[idx] = (short)f2bf(v);
        }
        if (tid < 192) {
            float sc = gamma[tid] * rsqrtf(rv[tid] + 1e-5f);
            bbg[tid] = b[tid] * sc + beta[tid] - rm[tid] * sc;
        }
    } else {
        const int e = (blockIdx.x - 1) * 1024 + tid * 4;
        const int o = e / 192;
        const float sc = gamma[o] * rsqrtf(rv[o] + 1e-5f);
        float4 w = *(const float4*)(W + e);
        short4v s4 = { (short)f2bf(w.x * sc), (short)f2bf(w.y * sc),
                       (short)f2bf(w.z * sc), (short)f2bf(w.w * sc) };
        *(short4v*)(Wpg + e) = s4;
    }
}

// ---------------------------------------------------------------------------
// Kernel B2b: W'' in MFMA-fragment order for kC2's coalesced wf loads.
// ---------------------------------------------------------------------------
__global__ void kB2b(const float* __restrict__ W, const float* __restrict__ gamma,
                     const float* __restrict__ rv, short* __restrict__ Wfrag) {
    const int idx = blockIdx.x * 256 + threadIdx.x;     // < 4608
    const int ot = idx / 384, r = idx - ot * 384;
    const int ks = r / 64, lane = r - ks * 64;
    const int o = ot * 16 + (lane & 15);
    const int k0 = ks * 32 + (lane >> 4) * 8;
    const float sc = gamma[o] * rsqrtf(rv[o] + 1e-5f);
    float4 w0 = *(const float4*)(W + o * 192 + k0);
    float4 w1 = *(const float4*)(W + o * 192 + k0 + 4);
    union { short4v h[2]; short8 v; } u;
    u.h[0] = cvt4(w0.x * sc, w0.y * sc, w0.z * sc, w0.w * sc);
    u.h[1] = cvt4(w1.x * sc, w1.y * sc, w1.z * sc, w1.w * sc);
    *(short8*)(Wfrag + (size_t)idx * 8) = u.v;
}

// ---------------------------------------------------------------------------
// PATH A kernel 1: GEMM1 -> agg2, fragment order with IN-REGISTER c-pair
// transpose: after shfl_xor(lane^1)+perm, each stored dword = (c, c+1) at
// ONE v.  agg2[((n*300+t)*6+wid)*1024 + lane*16 + j*2] (shorts).
// BARRIER-FREE: wave-private x staging (R14 loads) + wave-contiguous 2KB
// stores (R16).  grid (15,32)=480 blocks x 384 thr, TC=20 t/block.
// ---------------------------------------------------------------------------
#define TC1 20
__global__ __launch_bounds__(384, 4)
void kC1(const float* __restrict__ x, const short* __restrict__ bsTg,
         short* __restrict__ agg2) {
    __shared__ __align__(16) char xsb[2 * 12288];   // [slot][96 c][128 B], swizzled

    const int tid = threadIdx.x;
    const int lane = tid & 63;
    const int wid = tid >> 6;          // 0..5
    const int lam = lane & 15;
    const int kc = (lane >> 4) * 8;
    const int n = blockIdx.y;
    const int t0 = blockIdx.x * TC1;
    const int gb0 = n * 1440000 + t0 * 50;
    const int cgl = wid * 16 + lam;
    const bool oddl = lane & 1;

    // A_scale fragments in registers (identical across waves)
    short8 af[2][4];
#pragma unroll
    for (int ks = 0; ks < 2; ++ks)
#pragma unroll
        for (int m = 0; m < 4; ++m)
            af[ks][m] = *(const short8*)(bsTg + (m * 16 + lam) * 72 + ks * 32 + kc);

    // wave-private staging offsets: this wave's rows c in [wid*16, wid*16+16)
    int goff[7], loff[7];
#pragma unroll
    for (int i = 0; i < 7; ++i) {
        int idx = i * 64 + lane;                 // 0..447, valid < 400
        int idc = idx < 400 ? idx : 399;
        int cl = idc / 25, q = idc - cl * 25;
        int c = wid * 16 + cl;
        goff[i] = c * 15000 + 2 * q;
        loff[i] = (c * 128 + q * 4) ^ ((c & 7) << 4);
    }

    // zero u=50..63 pads for this wave's rows (both slots)
#pragma unroll
    for (int i = 0; i < 4; ++i) {
        int idx = i * 64 + lane;                 // < 224
        if (idx < 224) {
            int slot = idx / 112, rem = idx - slot * 112;
            int cl = rem / 7, k = rem - cl * 7;
            int c = wid * 16 + cl;
            *(unsigned int*)(xsb + slot * 12288 +
                ((c * 128 + (50 + 2 * k) * 2) ^ ((c & 7) << 4))) = 0;
        }
    }

    // prologue: stage t0 -> slot0, t1 -> slot1 (wave-private, no barrier)
    {
        f32x2 p0[7], p1[7];
#pragma unroll
        for (int i = 0; i < 7; ++i) p0[i] = *(const f32x2*)(x + gb0 + goff[i]);
#pragma unroll
        for (int i = 0; i < 7; ++i) p1[i] = *(const f32x2*)(x + gb0 + 50 + goff[i]);
#pragma unroll
        for (int i = 0; i < 7; ++i)
            if (i * 64 + lane < 400)
                *(unsigned int*)(xsb + loff[i]) = pack2(p0[i].x, p0[i].y);
#pragma unroll
        for (int i = 0; i < 7; ++i)
            if (i * 64 + lane < 400)
                *(unsigned int*)(xsb + 12288 + loff[i]) = pack2(p1[i].x, p1[i].y);
    }

    const f32x4 z = {0.f, 0.f, 0.f, 0.f};
    f32x2 pf[7];
    short* aout = agg2 + (((size_t)(n * 300 + t0) * 6 + wid) << 10) + (lane << 4);

#pragma unroll 1
    for (int tl = 0; tl < TC1; ++tl) {
        const int slot = tl & 1;

        // 1. issue t+2 loads early (hide under MFMA + swap + store)
        if (tl < TC1 - 2) {
            const float* xb2 = x + gb0 + (tl + 2) * 50;
#pragma unroll
            for (int i = 0; i < 7; ++i) pf[i] = *(const f32x2*)(xb2 + goff[i]);
        }

        // 2. GEMM1: D[v][c] for this wave's 16 c-columns
        short8 xb[2];
#pragma unroll
        for (int ks = 0; ks < 2; ++ks)
            xb[ks] = *(const short8*)(xsb + slot * 12288 +
                ((cgl * 128 + (ks * 32 + kc) * 2) ^ ((cgl & 7) << 4)));
        f32x4 acc1[4];
#pragma unroll
        for (int m = 0; m < 4; ++m) acc1[m] = z;
#pragma unroll
        for (int ks = 0; ks < 2; ++ks)
#pragma unroll
            for (int m = 0; m < 4; ++m)
                acc1[m] = __builtin_amdgcn_mfma_f32_16x16x32_bf16(af[ks][m], xb[ks], acc1[m], 0, 0, 0);

        // 3. pack (v,v+1)@c dwords, swap with lane^1, recombine to (c,c+1)@v
        unsigned int P[8], R[8];
#pragma unroll
        for (int m = 0; m < 4; ++m) {
            P[2 * m]     = pack2(acc1[m][0], acc1[m][1]);
            P[2 * m + 1] = pack2(acc1[m][2], acc1[m][3]);
        }
#pragma unroll
        for (int j = 0; j < 8; ++j) {
            unsigned int Q = (unsigned int)__shfl_xor((int)P[j], 1);
            R[j] = oddl ? ((Q >> 16) | (P[j] & 0xffff0000u))
                        : ((P[j] & 0xffffu) | (Q << 16));
        }
        // dword j=2m+p on lane: v = 16m + ((lane>>4)<<2) + 2p + (lane&1),
        // c-pair = wid*16 + ((lane&15)&~1).  Wave-contiguous 2KB store.
        {
            u32x4 s0 = {R[0], R[1], R[2], R[3]};
            u32x4 s1 = {R[4], R[5], R[6], R[7]};
            short* ap = aout + tl * 6144;
            *(u32x4*)(ap) = s0;
            *(u32x4*)(ap + 8) = s1;
        }

        // 4. write t+2 into the freed slot (same-wave DS ordering: safe)
        if (tl < TC1 - 2) {
            char* xw = xsb + slot * 12288;
#pragma unroll
            for (int i = 0; i < 7; ++i)
                if (i * 64 + lane < 400)
                    *(unsigned int*)(xw + loff[i]) = pack2(pf[i].x, pf[i].y);
        }
    }
}

// ---------------------------------------------------------------------------
// PATH A kernel 2: out = ReLU(W'' @ agg2 + bias).  grid (150,32) x 256 thr.
// Fill reads fragment dwords fully contiguous and writes each as ONE b32 to
// asb[row][k] (dword = (c,c+1) at one v; no short splits, 2-way banks).
// GEMM2 + stores = R16-verified code.
// ---------------------------------------------------------------------------
__global__ __launch_bounds__(256, 3)
void kC2(const short* __restrict__ agg2, const short* __restrict__ Wfrag,
         const float* __restrict__ bbg, float* __restrict__ out) {
    __shared__ __align__(16) short asb[64][200];    // 25600 B

    const int tid = threadIdx.x;
    const int lane = tid & 63;
    const int wid = tid >> 6;          // 0..3
    const int lam = lane & 15;
    const int kc = (lane >> 4) * 8;
    const int cb = (lane >> 4) * 4;
    const int n = blockIdx.y;
    const int bx = blockIdx.x;         // t = 2bx, 2bx+1

    // W'' fragments (coalesced) + bias
    short8 wf[3][6];
    float bb[3];
#pragma unroll
    for (int j = 0; j < 3; ++j) {
        const int ot = wid * 3 + j;
#pragma unroll
        for (int ks = 0; ks < 6; ++ks)
            wf[j][ks] = *(const short8*)(Wfrag + ((size_t)(ot * 6 + ks) * 64 + lane) * 8);
        bb[j] = bbg[ot * 16 + lam];
    }

    // fill: fragment dwords -> asb[tl*25+vs][(s*96+c)/2] as b32
    {
        const unsigned int* src = (const unsigned int*)agg2
            + (size_t)(n * 300 + 2 * bx) * 3072;
        unsigned int* asbd = (unsigned int*)&asb[0][0];
#pragma unroll
        for (int k = 0; k < 24; ++k) {
            int i = k * 256 + tid;                  // 0..6143
            unsigned int w = src[i];
            int tl = i >= 3072;
            int d = i - tl * 3072;
            int wid_s = d >> 9, rem = d & 511;
            int lane_s = rem >> 3, j = rem & 7;
            int m = j >> 1, p = j & 1;
            int v = 16 * m + (((lane_s >> 4) & 3) << 2) + 2 * p + (lane_s & 1);
            int c = wid_s * 16 + ((lane_s & 15) & 0xE);
            if (v < 50) {
                int s = v >= 25;
                int row = tl * 25 + v - 25 * s;
                asbd[row * 100 + 48 * s + (c >> 1)] = w;
            }
        }
    }
    __syncthreads();

    const f32x4 z = {0.f, 0.f, 0.f, 0.f};
    f32x4 acc[4][3];
#pragma unroll
    for (int m = 0; m < 4; ++m)
#pragma unroll
        for (int j = 0; j < 3; ++j) acc[m][j] = z;

#pragma unroll
    for (int ks = 0; ks < 6; ++ks) {
        short8 a[4];
#pragma unroll
        for (int m = 0; m < 4; ++m)
            a[m] = *(const short8*)(&asb[m * 16 + lam][ks * 32 + kc]);
#pragma unroll
        for (int m = 0; m < 4; ++m)
#pragma unroll
            for (int j = 0; j < 3; ++j)
                acc[m][j] = __builtin_amdgcn_mfma_f32_16x16x32_bf16(a[m], wf[j][ks], acc[m][j], 0, 0, 0);
    }

    // stores: row = m*16+cb+r in [0,50); out offset = (n*192+o)*7500 + bx*50 + row
#pragma unroll
    for (int m = 0; m < 4; ++m) {
        const int tvb = m * 16 + cb;
        if (tvb < 50) {
#pragma unroll
            for (int j = 0; j < 3; ++j) {
                const int o = (wid * 3 + j) * 16 + lam;
                float* op = out + (size_t)(n * 192 + o) * 7500 + bx * 50 + tvb;
                float v0 = acc[m][j][0] + bb[j]; v0 = v0 > 0.f ? v0 : 0.f;
                float v1 = acc[m][j][1] + bb[j]; v1 = v1 > 0.f ? v1 : 0.f;
                f32x2 p0 = {v0, v1};
                *(f32x2*)op = p0;
                if (tvb < 48) {                     // rows 48,49 tail has only 2 valid
                    float v2 = acc[m][j][2] + bb[j]; v2 = v2 > 0.f ? v2 : 0.f;
                    float v3 = acc[m][j][3] + bb[j]; v3 = v3 > 0.f ? v3 : 0.f;
                    f32x2 p1 = {v2, v3};
                    *(f32x2*)(op + 2) = p1;
                }
            }
        }
    }
}

// ---------------------------------------------------------------------------
// PATH B fallback (== R11 fused kernel), used when ws is too small.
// ---------------------------------------------------------------------------
__device__ __forceinline__ void ldx_fb(const float* __restrict__ x, int gbase,
                                       f32x2 (&pf)[7], int tid) {
#pragma unroll
    for (int i = 0; i < 7; ++i) {
        int idx = i * 384 + tid;
        idx = idx < 2400 ? idx : 2399;
        int c = idx / 25, q = idx - c * 25;
        pf[i] = *(const f32x2*)(x + gbase + c * 15000 + 2 * q);
    }
}
__device__ __forceinline__ void stx_fb(char* xsb, int slot, const f32x2 (&pf)[7], int tid) {
#pragma unroll
    for (int i = 0; i < 7; ++i) {
        int idx = i * 384 + tid;
        if (idx < 2400) {
            int c = idx / 25, q = idx - c * 25;
            *(unsigned int*)(xsb + ((slot * 12288 + c * 128 + q * 4) ^ ((c & 7) << 4)))
                = pack2(pf[i].x, pf[i].y);
        }
    }
}

__global__ __launch_bounds__(384, 3)
void kC(const float* __restrict__ x, const short* __restrict__ Wpg,
        const short* __restrict__ bsTg, const float* __restrict__ bbg,
        float* __restrict__ out) {
    __shared__ __align__(16) char xsb[2 * 12288];
    __shared__ __align__(16) short bsT[64 * 72];
    __shared__ __align__(16) short a2T[2][32][208];

    const int tid = threadIdx.x;
    const int lane = tid & 63;
    const int wid = tid >> 6;
    const int lam = lane & 15;
    const int kc = (lane >> 4) * 8;
    const int cb = (lane >> 4) * 4;
    const int n = blockIdx.y;
    const int t0 = blockIdx.x * 4;
    const int gb0 = n * 1440000 + t0 * 50;
    const int cgl = wid * 16 + lam;

    f32x2 pf2[13];
#pragma unroll
    for (int i = 0; i < 13; ++i) {
        int idx = i * 384 + tid;
        idx = idx < 4800 ? idx : 4799;
        int c = idx / 50, q2 = idx - c * 50;
        int tl = q2 >= 25, q = q2 - 25 * tl;
        pf2[i] = *(const f32x2*)(x + gb0 + c * 15000 + tl * 50 + 2 * q);
    }
    short8 wf[2][6];
#pragma unroll
    for (int ot = 0; ot < 2; ++ot)
#pragma unroll
        for (int ks = 0; ks < 6; ++ks)
            wf[ot][ks] = *(const short8*)(Wpg + ((2 * wid + ot) * 16 + lam) * 192 + ks * 32 + kc);
    float bb[2];
#pragma unroll
    for (int ot = 0; ot < 2; ++ot) bb[ot] = bbg[(2 * wid + ot) * 16 + lam];
    {
        const int4* src = (const int4*)bsTg;
        int4* dst = (int4*)bsT;
        for (int i = tid; i < 576; i += 384) dst[i] = src[i];
    }
    for (int idx = tid; idx < 1344; idx += 384) {
        int r = idx / 7, k = idx - r * 7;
        int slot = r / 96, c = r - 96 * slot;
        *(unsigned int*)(xsb + ((slot * 12288 + c * 128 + (50 + 2 * k) * 2) ^ ((c & 7) << 4))) = 0;
    }
    for (int idx = tid; idx < 1456; idx += 384) {
        int buf = idx / 728, rem = idx - buf * 728;
        int row = 25 + rem / 104, col2 = rem - (rem / 104) * 104;
        *((unsigned int*)&a2T[buf][row][0] + col2) = 0;
    }
#pragma unroll
    for (int i = 0; i < 13; ++i) {
        int idx = i * 384 + tid;
        if (idx < 4800) {
            int c = idx / 50, q2 = idx - c * 50;
            int tl = q2 >= 25, q = q2 - 25 * tl;
            *(unsigned int*)(xsb + ((tl * 12288 + c * 128 + q * 4) ^ ((c & 7) << 4)))
                = pack2(pf2[i].x, pf2[i].y);
        }
    }
    asm volatile("s_waitcnt lgkmcnt(0)" ::: "memory");
    __builtin_amdgcn_s_barrier();

    const f32x4 z = {0.f, 0.f, 0.f, 0.f};
    f32x2 pf[7];

#pragma unroll 1
    for (int tl = 0; tl < 4; ++tl) {
        const int slot = tl & 1;
        short* a2w = &a2T[slot][0][0];
        if (tl < 2) ldx_fb(x, gb0 + (tl + 2) * 50, pf, tid);

        short8 xb[2];
#pragma unroll
        for (int ks = 0; ks < 2; ++ks)
            xb[ks] = *(const short8*)(xsb +
                ((slot * 12288 + cgl * 128 + (ks * 32 + kc) * 2) ^ ((cgl & 7) << 4)));
        f32x4 acc1[4];
#pragma unroll
        for (int m = 0; m < 4; ++m) acc1[m] = z;
#pragma unroll
        for (int ks = 0; ks < 2; ++ks)
#pragma unroll
            for (int m = 0; m < 4; ++m) {
                const short8 af = *(const short8*)(bsT + (m * 16 + lam) * 72 + ks * 32 + kc);
                acc1[m] = __builtin_amdgcn_mfma_f32_16x16x32_bf16(af, xb[ks], acc1[m], 0, 0, 0);
            }
#pragma unroll
        for (int m = 0; m < 3; ++m) {
            short4v sv = cvt4(acc1[m][0], acc1[m][1], acc1[m][2], acc1[m][3]);
#pragma unroll
            for (int r = 0; r < 4; ++r) {
                const int v = m * 16 + cb + r;
                const int s = v >= 25;
                a2w[(v - 25 * s) * 208 + s * 96 + cgl] = sv[r];
            }
        }
        if (cb == 0) {
            a2w[23 * 208 + 96 + cgl] = (short)f2bf(acc1[3][0]);
            a2w[24 * 208 + 96 + cgl] = (short)f2bf(acc1[3][1]);
        }
        asm volatile("s_waitcnt lgkmcnt(0)" ::: "memory");
        __builtin_amdgcn_s_barrier();

        f32x4 acc2[2][2];
#pragma unroll
        for (int g = 0; g < 2; ++g) { acc2[g][0] = z; acc2[g][1] = z; }
#pragma unroll
        for (int ks = 0; ks < 6; ++ks) {
            const short8 A0 = *(const short8*)(a2w + lam * 208 + ks * 32 + kc);
            const short8 A1 = *(const short8*)(a2w + (16 + lam) * 208 + ks * 32 + kc);
#pragma unroll
            for (int ot = 0; ot < 2; ++ot) {
                acc2[0][ot] = __builtin_amdgcn_mfma_f32_16x16x32_bf16(A0, wf[ot][ks], acc2[0][ot], 0, 0, 0);
                acc2[1][ot] = __builtin_amdgcn_mfma_f32_16x16x32_bf16(A1, wf[ot][ks], acc2[1][ot], 0, 0, 0);
            }
        }
        if (tl < 2) stx_fb(xsb, slot, pf, tid);

        const int t = t0 + tl;
#pragma unroll
        for (int ot = 0; ot < 2; ++ot) {
            const int o = (2 * wid + ot) * 16 + lam;
            float* op = out + ((size_t)(n * 192 + o) * 300 + t) * 25;
#pragma unroll
            for (int r = 0; r < 4; ++r) {
                float vv = acc2[0][ot][r] + bb[ot];
                op[cb + r] = vv > 0.f ? vv : 0.f;
            }
#pragma unroll
            for (int r = 0; r < 4; ++r) {
                const int tv = 16 + cb + r;
                if (tv < 25) {
                    float vv = acc2[1][ot][r] + bb[ot];
                    op[tv] = vv > 0.f ? vv : 0.f;
                }
            }
        }
    }
}

// ---------------------------------------------------------------------------
extern "C" void kernel_launch(void* const* d_in, const int* in_sizes, int n_in,
                              void* d_out, int out_size, void* d_ws, size_t ws_size,
                              hipStream_t stream) {
    const float* x     = (const float*)d_in[0];
    const float* xx    = (const float*)d_in[1];
    const float* A_res = (const float*)d_in[2];
    const float* W     = (const float*)d_in[3];
    const float* b     = (const float*)d_in[4];
    const float* gamma = (const float*)d_in[5];
    const float* beta  = (const float*)d_in[6];
    const float* rm    = (const float*)d_in[7];
    const float* rv    = (const float*)d_in[8];
    float* out = (float*)d_out;

    char* ws = (char*)d_ws;
    float* At_part  = (float*)ws;                    // 400000 B
    float* Acontrib = (float*)(ws + 400000);         //  80000 B
    short* bsTg     = (short*)(ws + 480000);         //   9216 B
    short* Wpg      = (short*)(ws + 489216);         //  73728 B
    float* bbg      = (float*)(ws + 562944);         //    768 B
    short* Wfrag    = (short*)(ws + 563712);         //  73728 B -> ends 637440
    short* agg2     = (short*)(ws + 637440);         // 117964800 B (PATH A only)
    const bool bigws = ws_size >= (size_t)637440 + 117964800u;

    kA<<<dim3(5, 32), 256, 0, stream>>>(xx, At_part);
    kB1<<<32, 256, 0, stream>>>(At_part, Acontrib);
    kB2<<<37, 256, 0, stream>>>(Acontrib, A_res, W, b, gamma, beta, rm, rv, bsTg, Wpg, bbg);
    kB2b<<<18, 256, 0, stream>>>(W, gamma, rv, Wfrag);

    if (bigws) {
        kC1<<<dim3(15, 32), 384, 0, stream>>>(x, bsTg, agg2);
        kC2<<<dim3(150, 32), 256, 0, stream>>>(agg2, Wfrag, bbg, out);
    } else {
        kC<<<dim3(75, 32), 384, 0, stream>>>(x, Wpg, bsTg, bbg, out);
    }
}

// Round 18
// 186.913 us; speedup vs baseline: 1.2658x; 1.2372x over previous
//
#include <hip/hip_runtime.h>
#include <hip/hip_bf16.h>

typedef __attribute__((ext_vector_type(8))) short short8;
typedef __attribute__((ext_vector_type(4))) short short4v;
typedef __attribute__((ext_vector_type(4))) float f32x4;
typedef __attribute__((ext_vector_type(2))) float f32x2;

__device__ __forceinline__ unsigned short f2bf(float f) {
    unsigned int u = __builtin_bit_cast(unsigned int, f);
    u += 0x7fffu + ((u >> 16) & 1u);   // round-to-nearest-even
    return (unsigned short)(u >> 16);
}
__device__ __forceinline__ unsigned int pack2(float a, float b) {
    union { __hip_bfloat162 h; unsigned int u; } r;
    r.h = __float22bfloat162_rn(make_float2(a, b));
    return r.u;
}
__device__ __forceinline__ short4v cvt4(float a, float b, float c, float d) {
    union { __hip_bfloat162 h[2]; short4v s; } u;
    u.h[0] = __float22bfloat162_rn(make_float2(a, b));
    u.h[1] = __float22bfloat162_rn(make_float2(c, d));
    return u.s;
}

// ---------------------------------------------------------------------------
// Kernel A: partial adjacency sums over 60-frame chunks. grid (5,32).
// ---------------------------------------------------------------------------
__global__ void kA(const float* __restrict__ xx, float* __restrict__ At_part) {
    __shared__ float xs3[3][60][25];
    const int tc = blockIdx.x, n = blockIdx.y;
    const int tid = threadIdx.x;
    const float* base = xx + (size_t)n * 22500 + tc * 1500;
    for (int idx = tid; idx < 4500; idx += 256) {
        int ch = idx / 1500, rt = idx % 1500;
        xs3[ch][rt / 25][rt % 25] = base[ch * 7500 + rt];
    }
    __syncthreads();
    for (int p = tid; p < 625; p += 256) {
        int v = p / 25, u = p % 25;
        float s = 0.f;
        for (int t = 0; t < 60; ++t) {
            float dx = xs3[0][t][v] - xs3[0][t][u];
            float dy = xs3[1][t][v] - xs3[1][t][u];
            float dz = xs3[2][t][v] - xs3[2][t][u];
            s += __expf(-2.f * (dx * dx + dy * dy + dz * dz));
        }
        At_part[(size_t)(n * 5 + tc) * 625 + p] = s;
    }
}

// ---------------------------------------------------------------------------
// Kernel B1: per-sample reduce + symmetric normalization. grid 32.
// ---------------------------------------------------------------------------
__global__ void kB1(const float* __restrict__ At_part, float* __restrict__ Acontrib) {
    __shared__ float At[625];
    __shared__ float dinv[25];
    const int n = blockIdx.x, tid = threadIdx.x;
    for (int p = tid; p < 625; p += 256) {
        float s = 0.f;
        for (int tc = 0; tc < 5; ++tc) s += At_part[(size_t)(n * 5 + tc) * 625 + p];
        At[p] = s;
    }
    __syncthreads();
    if (tid < 25) {
        float d = 0.f;
        for (int u = 0; u < 25; ++u) d += At[tid * 25 + u];
        dinv[tid] = rsqrtf(d * (1.f / 300.f));
    }
    __syncthreads();
    for (int p = tid; p < 625; p += 256)
        Acontrib[n * 625 + p] = At[p] * (1.f / 300.f) * dinv[p / 25] * dinv[p % 25] * (1.f / 32.f);
}

// ---------------------------------------------------------------------------
// Kernel B2: block 0 -> bsTg (bf16 [64][72], zero-padded) + fused bias;
//            blocks 1..36 -> W'' = W * bn_scale  (layout [o][k], row-major).
// ---------------------------------------------------------------------------
__global__ void kB2(const float* __restrict__ Acontrib, const float* __restrict__ A_res,
                    const float* __restrict__ W, const float* __restrict__ b,
                    const float* __restrict__ gamma, const float* __restrict__ beta,
                    const float* __restrict__ rm, const float* __restrict__ rv,
                    short* __restrict__ bsTg, short* __restrict__ Wpg,
                    float* __restrict__ bbg) {
    const int tid = threadIdx.x;
    if (blockIdx.x == 0) {
        __shared__ float macc[625];
        for (int p = tid; p < 625; p += 256) {
            float s = 0.f;
            for (int n = 0; n < 32; ++n) s += Acontrib[n * 625 + p];
            macc[p] = s;
        }
        __syncthreads();
        for (int idx = tid; idx < 64 * 72; idx += 256) {
            int col = idx / 72, u = idx % 72;
            float v = 0.f;
            if (col < 50 && u < 50) v = macc[(col % 25) * 25 + (u % 25)] + A_res[col * 50 + u];
            bsTg[idx] = (short)f2bf(v);
        }
        if (tid < 192) {
            float sc = gamma[tid] * rsqrtf(rv[tid] + 1e-5f);
            bbg[tid] = b[tid] * sc + beta[tid] - rm[tid] * sc;
        }
    } else {
        const int e = (blockIdx.x - 1) * 1024 + tid * 4;
        const int o = e / 192;
        const float sc = gamma[o] * rsqrtf(rv[o] + 1e-5f);
        float4 w = *(const float4*)(W + e);
        short4v s4 = { (short)f2bf(w.x * sc), (short)f2bf(w.y * sc),
                       (short)f2bf(w.z * sc), (short)f2bf(w.w * sc) };
        *(short4v*)(Wpg + e) = s4;
    }
}

// ---------------------------------------------------------------------------
// Kernel B2b: W'' in MFMA-fragment order for kC2's coalesced wf loads.
// ---------------------------------------------------------------------------
__global__ void kB2b(const float* __restrict__ W, const float* __restrict__ gamma,
                     const float* __restrict__ rv, short* __restrict__ Wfrag) {
    const int idx = blockIdx.x * 256 + threadIdx.x;     // < 4608
    const int ot = idx / 384, r = idx - ot * 384;
    const int ks = r / 64, lane = r - ks * 64;
    const int o = ot * 16 + (lane & 15);
    const int k0 = ks * 32 + (lane >> 4) * 8;
    const float sc = gamma[o] * rsqrtf(rv[o] + 1e-5f);
    float4 w0 = *(const float4*)(W + o * 192 + k0);
    float4 w1 = *(const float4*)(W + o * 192 + k0 + 4);
    union { short4v h[2]; short8 v; } u;
    u.h[0] = cvt4(w0.x * sc, w0.y * sc, w0.z * sc, w0.w * sc);
    u.h[1] = cvt4(w1.x * sc, w1.y * sc, w1.z * sc, w1.w * sc);
    *(short8*)(Wfrag + (size_t)idx * 8) = u.v;
}

// ---------------------------------------------------------------------------
// PATH A kernel 1: GEMM1 -> agg2[n][tv][k] bf16 DIRECTLY (no LDS transpose,
// no dump pass, no barriers).  In-register c-pair transpose (shfl lane^1),
// then per-lane dword stores at precomputed voff[j]: each instruction writes
// 8 v-rows x 32B contiguous; the block's 6 waves fill adjacent 32B chunks of
// the same rows concurrently -> L2 merges to full lines.
// grid (15,32)=480 x 384 thr, TC=20 t/block, wave-private x staging.
// ---------------------------------------------------------------------------
#define TC1 20
__global__ __launch_bounds__(384, 4)
void kC1(const float* __restrict__ x, const short* __restrict__ bsTg,
         short* __restrict__ agg2) {
    __shared__ __align__(16) char xsb[2 * 12288];   // [slot][96 c][128 B], swizzled

    const int tid = threadIdx.x;
    const int lane = tid & 63;
    const int wid = tid >> 6;          // 0..5
    const int lam = lane & 15;
    const int kc = (lane >> 4) * 8;
    const int n = blockIdx.y;
    const int t0 = blockIdx.x * TC1;
    const int gb0 = n * 1440000 + t0 * 50;
    const int cgl = wid * 16 + lam;
    const bool oddl = lane & 1;

    // A_scale fragments in registers (identical across waves)
    short8 af[2][4];
#pragma unroll
    for (int ks = 0; ks < 2; ++ks)
#pragma unroll
        for (int m = 0; m < 4; ++m)
            af[ks][m] = *(const short8*)(bsTg + (m * 16 + lam) * 72 + ks * 32 + kc);

    // wave-private staging offsets: this wave's rows c in [wid*16, wid*16+16)
    int goff[7], loff[7];
#pragma unroll
    for (int i = 0; i < 7; ++i) {
        int idx = i * 64 + lane;                 // 0..447, valid < 400
        int idc = idx < 400 ? idx : 399;
        int cl = idc / 25, q = idc - cl * 25;
        int c = wid * 16 + cl;
        goff[i] = c * 15000 + 2 * q;
        loff[i] = (c * 128 + q * 4) ^ ((c & 7) << 4);
    }

    // per-lane store offsets: dword j=2m+p -> v = 16m+4hi+2p+(lane&1)
    int voff[7];
#pragma unroll
    for (int j = 0; j < 7; ++j) {
        int m = j >> 1, p = j & 1;
        int v = 16 * m + 4 * (lane >> 4) + 2 * p + (lane & 1);
        int s = v >= 25;
        int vs = v - 25 * s;
        voff[j] = vs * 96 + s * 48 + wid * 8 + (lam >> 1);
    }
    const bool j6ok = (lane >> 4) == 0;          // j=6 valid only v=48,49

    // zero u=50..63 pads for this wave's rows (both slots)
#pragma unroll
    for (int i = 0; i < 4; ++i) {
        int idx = i * 64 + lane;                 // < 224
        if (idx < 224) {
            int slot = idx / 112, rem = idx - slot * 112;
            int cl = rem / 7, k = rem - cl * 7;
            int c = wid * 16 + cl;
            *(unsigned int*)(xsb + slot * 12288 +
                ((c * 128 + (50 + 2 * k) * 2) ^ ((c & 7) << 4))) = 0;
        }
    }

    // prologue: stage t0 -> slot0, t1 -> slot1 (wave-private, no barrier)
    {
        f32x2 p0[7], p1[7];
#pragma unroll
        for (int i = 0; i < 7; ++i) p0[i] = *(const f32x2*)(x + gb0 + goff[i]);
#pragma unroll
        for (int i = 0; i < 7; ++i) p1[i] = *(const f32x2*)(x + gb0 + 50 + goff[i]);
#pragma unroll
        for (int i = 0; i < 7; ++i)
            if (i * 64 + lane < 400)
                *(unsigned int*)(xsb + loff[i]) = pack2(p0[i].x, p0[i].y);
#pragma unroll
        for (int i = 0; i < 7; ++i)
            if (i * 64 + lane < 400)
                *(unsigned int*)(xsb + 12288 + loff[i]) = pack2(p1[i].x, p1[i].y);
    }

    const f32x4 z = {0.f, 0.f, 0.f, 0.f};
    f32x2 pf[7];
    unsigned int* adst = (unsigned int*)agg2 + (size_t)n * 720000 + (size_t)t0 * 2400;

#pragma unroll 1
    for (int tl = 0; tl < TC1; ++tl) {
        const int slot = tl & 1;

        // 1. issue t+2 loads early (hide under MFMA + swap + stores)
        if (tl < TC1 - 2) {
            const float* xb2 = x + gb0 + (tl + 2) * 50;
#pragma unroll
            for (int i = 0; i < 7; ++i) pf[i] = *(const f32x2*)(xb2 + goff[i]);
        }

        // 2. GEMM1: D[v][c] for this wave's 16 c-columns
        short8 xb[2];
#pragma unroll
        for (int ks = 0; ks < 2; ++ks)
            xb[ks] = *(const short8*)(xsb + slot * 12288 +
                ((cgl * 128 + (ks * 32 + kc) * 2) ^ ((cgl & 7) << 4)));
        f32x4 acc1[4];
#pragma unroll
        for (int m = 0; m < 4; ++m) acc1[m] = z;
#pragma unroll
        for (int ks = 0; ks < 2; ++ks)
#pragma unroll
            for (int m = 0; m < 4; ++m)
                acc1[m] = __builtin_amdgcn_mfma_f32_16x16x32_bf16(af[ks][m], xb[ks], acc1[m], 0, 0, 0);

        // 3. pack (v,v+1)@c dwords, swap with lane^1, recombine to (c,c+1)@v
        unsigned int P[7], R[7];
#pragma unroll
        for (int m = 0; m < 4; ++m) {
            P[2 * m] = pack2(acc1[m][0], acc1[m][1]);
            if (m < 3) P[2 * m + 1] = pack2(acc1[m][2], acc1[m][3]);
        }
#pragma unroll
        for (int j = 0; j < 7; ++j) {
            unsigned int Q = (unsigned int)__shfl_xor((int)P[j], 1);
            R[j] = oddl ? ((Q >> 16) | (P[j] & 0xffff0000u))
                        : ((P[j] & 0xffffu) | (Q << 16));
        }
        // 4. direct dword stores into agg2[n][tv][k]
        {
            unsigned int* at = adst + tl * 2400;
            at[voff[0]] = R[0];
            at[voff[1]] = R[1];
            at[voff[2]] = R[2];
            at[voff[3]] = R[3];
            at[voff[4]] = R[4];
            at[voff[5]] = R[5];
            if (j6ok) at[voff[6]] = R[6];
        }

        // 5. write t+2 into the freed slot (same-wave DS ordering: safe)
        if (tl < TC1 - 2) {
            char* xw = xsb + slot * 12288;
#pragma unroll
            for (int i = 0; i < 7; ++i)
                if (i * 64 + lane < 400)
                    *(unsigned int*)(xw + loff[i]) = pack2(pf[i].x, pf[i].y);
        }
    }
}

// ---------------------------------------------------------------------------
// PATH A kernel 2 (verbatim R12, proven ~60us): out = ReLU(W''@agg2 + bias).
// grid (118,32) x 256 thr; contiguous tile stage; coalesced wf; float4 stores.
// ---------------------------------------------------------------------------
__global__ __launch_bounds__(256, 3)
void kC2(const short* __restrict__ agg2, const short* __restrict__ Wfrag,
         const float* __restrict__ bbg, float* __restrict__ out) {
    __shared__ __align__(16) unsigned int asb[64 * 100];

    const int tid = threadIdx.x;
    const int lane = tid & 63;
    const int wid = tid >> 6;
    const int lam = lane & 15;
    const int kc = (lane >> 4) * 8;
    const int cb = (lane >> 4) * 4;
    const int n = blockIdx.y;
    const int tv0 = blockIdx.x * 64;

    short8 wf[3][6];
    float bb[3];
#pragma unroll
    for (int j = 0; j < 3; ++j) {
        const int ot = wid * 3 + j;
#pragma unroll
        for (int ks = 0; ks < 6; ++ks)
            wf[j][ks] = *(const short8*)(Wfrag + ((size_t)(ot * 6 + ks) * 64 + lane) * 8);
        bb[j] = bbg[ot * 16 + lam];
    }

    {
        const unsigned int* src = (const unsigned int*)agg2 + (size_t)n * 720000;
#pragma unroll
        for (int k = 0; k < 24; ++k) {
            int d = k * 256 + tid;
            int row = d / 96, c2 = d - row * 96;
            int tvg = tv0 + row;
            tvg = tvg < 7500 ? tvg : 7499;
            asb[row * 100 + c2] = src[(size_t)tvg * 96 + c2];
        }
    }
    __syncthreads();

    const f32x4 z = {0.f, 0.f, 0.f, 0.f};
    f32x4 acc[4][3];
#pragma unroll
    for (int m = 0; m < 4; ++m)
#pragma unroll
        for (int j = 0; j < 3; ++j) acc[m][j] = z;

#pragma unroll
    for (int ks = 0; ks < 6; ++ks) {
        short8 a[4];
#pragma unroll
        for (int m = 0; m < 4; ++m)
            a[m] = *(const short8*)((const short*)asb + (m * 16 + lam) * 200 + ks * 32 + kc);
#pragma unroll
        for (int m = 0; m < 4; ++m)
#pragma unroll
            for (int j = 0; j < 3; ++j)
                acc[m][j] = __builtin_amdgcn_mfma_f32_16x16x32_bf16(a[m], wf[j][ks], acc[m][j], 0, 0, 0);
    }

#pragma unroll
    for (int m = 0; m < 4; ++m) {
        const int tvg = tv0 + m * 16 + cb;
        if (tvg < 7500) {
#pragma unroll
            for (int j = 0; j < 3; ++j) {
                const int o = (wid * 3 + j) * 16 + lam;
                float4 v;
                v.x = acc[m][j][0] + bb[j]; v.x = v.x > 0.f ? v.x : 0.f;
                v.y = acc[m][j][1] + bb[j]; v.y = v.y > 0.f ? v.y : 0.f;
                v.z = acc[m][j][2] + bb[j]; v.z = v.z > 0.f ? v.z : 0.f;
                v.w = acc[m][j][3] + bb[j]; v.w = v.w > 0.f ? v.w : 0.f;
                *(float4*)(out + (size_t)(n * 192 + o) * 7500 + tvg) = v;
            }
        }
    }
}

// ---------------------------------------------------------------------------
// PATH B fallback (== R11 fused kernel), used when ws is too small.
// ---------------------------------------------------------------------------
__device__ __forceinline__ void ldx_fb(const float* __restrict__ x, int gbase,
                                       f32x2 (&pf)[7], int tid) {
#pragma unroll
    for (int i = 0; i < 7; ++i) {
        int idx = i * 384 + tid;
        idx = idx < 2400 ? idx : 2399;
        int c = idx / 25, q = idx - c * 25;
        pf[i] = *(const f32x2*)(x + gbase + c * 15000 + 2 * q);
    }
}
__device__ __forceinline__ void stx_fb(char* xsb, int slot, const f32x2 (&pf)[7], int tid) {
#pragma unroll
    for (int i = 0; i < 7; ++i) {
        int idx = i * 384 + tid;
        if (idx < 2400) {
            int c = idx / 25, q = idx - c * 25;
            *(unsigned int*)(xsb + ((slot * 12288 + c * 128 + q * 4) ^ ((c & 7) << 4)))
                = pack2(pf[i].x, pf[i].y);
        }
    }
}

__global__ __launch_bounds__(384, 3)
void kC(const float* __restrict__ x, const short* __restrict__ Wpg,
        const short* __restrict__ bsTg, const float* __restrict__ bbg,
        float* __restrict__ out) {
    __shared__ __align__(16) char xsb[2 * 12288];
    __shared__ __align__(16) short bsT[64 * 72];
    __shared__ __align__(16) short a2T[2][32][208];

    const int tid = threadIdx.x;
    const int lane = tid & 63;
    const int wid = tid >> 6;
    const int lam = lane & 15;
    const int kc = (lane >> 4) * 8;
    const int cb = (lane >> 4) * 4;
    const int n = blockIdx.y;
    const int t0 = blockIdx.x * 4;
    const int gb0 = n * 1440000 + t0 * 50;
    const int cgl = wid * 16 + lam;

    f32x2 pf2[13];
#pragma unroll
    for (int i = 0; i < 13; ++i) {
        int idx = i * 384 + tid;
        idx = idx < 4800 ? idx : 4799;
        int c = idx / 50, q2 = idx - c * 50;
        int tl = q2 >= 25, q = q2 - 25 * tl;
        pf2[i] = *(const f32x2*)(x + gb0 + c * 15000 + tl * 50 + 2 * q);
    }
    short8 wf[2][6];
#pragma unroll
    for (int ot = 0; ot < 2; ++ot)
#pragma unroll
        for (int ks = 0; ks < 6; ++ks)
            wf[ot][ks] = *(const short8*)(Wpg + ((2 * wid + ot) * 16 + lam) * 192 + ks * 32 + kc);
    float bb[2];
#pragma unroll
    for (int ot = 0; ot < 2; ++ot) bb[ot] = bbg[(2 * wid + ot) * 16 + lam];
    {
        const int4* src = (const int4*)bsTg;
        int4* dst = (int4*)bsT;
        for (int i = tid; i < 576; i += 384) dst[i] = src[i];
    }
    for (int idx = tid; idx < 1344; idx += 384) {
        int r = idx / 7, k = idx - r * 7;
        int slot = r / 96, c = r - 96 * slot;
        *(unsigned int*)(xsb + ((slot * 12288 + c * 128 + (50 + 2 * k) * 2) ^ ((c & 7) << 4))) = 0;
    }
    for (int idx = tid; idx < 1456; idx += 384) {
        int buf = idx / 728, rem = idx - buf * 728;
        int row = 25 + rem / 104, col2 = rem - (rem / 104) * 104;
        *((unsigned int*)&a2T[buf][row][0] + col2) = 0;
    }
#pragma unroll
    for (int i = 0; i < 13; ++i) {
        int idx = i * 384 + tid;
        if (idx < 4800) {
            int c = idx / 50, q2 = idx - c * 50;
            int tl = q2 >= 25, q = q2 - 25 * tl;
            *(unsigned int*)(xsb + ((tl * 12288 + c * 128 + q * 4) ^ ((c & 7) << 4)))
                = pack2(pf2[i].x, pf2[i].y);
        }
    }
    asm volatile("s_waitcnt lgkmcnt(0)" ::: "memory");
    __builtin_amdgcn_s_barrier();

    const f32x4 z = {0.f, 0.f, 0.f, 0.f};
    f32x2 pf[7];

#pragma unroll 1
    for (int tl = 0; tl < 4; ++tl) {
        const int slot = tl & 1;
        short* a2w = &a2T[slot][0][0];
        if (tl < 2) ldx_fb(x, gb0 + (tl + 2) * 50, pf, tid);

        short8 xb[2];
#pragma unroll
        for (int ks = 0; ks < 2; ++ks)
            xb[ks] = *(const short8*)(xsb +
                ((slot * 12288 + cgl * 128 + (ks * 32 + kc) * 2) ^ ((cgl & 7) << 4)));
        f32x4 acc1[4];
#pragma unroll
        for (int m = 0; m < 4; ++m) acc1[m] = z;
#pragma unroll
        for (int ks = 0; ks < 2; ++ks)
#pragma unroll
            for (int m = 0; m < 4; ++m) {
                const short8 af = *(const short8*)(bsT + (m * 16 + lam) * 72 + ks * 32 + kc);
                acc1[m] = __builtin_amdgcn_mfma_f32_16x16x32_bf16(af, xb[ks], acc1[m], 0, 0, 0);
            }
#pragma unroll
        for (int m = 0; m < 3; ++m) {
            short4v sv = cvt4(acc1[m][0], acc1[m][1], acc1[m][2], acc1[m][3]);
#pragma unroll
            for (int r = 0; r < 4; ++r) {
                const int v = m * 16 + cb + r;
                const int s = v >= 25;
                a2w[(v - 25 * s) * 208 + s * 96 + cgl] = sv[r];
            }
        }
        if (cb == 0) {
            a2w[23 * 208 + 96 + cgl] = (short)f2bf(acc1[3][0]);
            a2w[24 * 208 + 96 + cgl] = (short)f2bf(acc1[3][1]);
        }
        asm volatile("s_waitcnt lgkmcnt(0)" ::: "memory");
        __builtin_amdgcn_s_barrier();

        f32x4 acc2[2][2];
#pragma unroll
        for (int g = 0; g < 2; ++g) { acc2[g][0] = z; acc2[g][1] = z; }
#pragma unroll
        for (int ks = 0; ks < 6; ++ks) {
            const short8 A0 = *(const short8*)(a2w + lam * 208 + ks * 32 + kc);
            const short8 A1 = *(const short8*)(a2w + (16 + lam) * 208 + ks * 32 + kc);
#pragma unroll
            for (int ot = 0; ot < 2; ++ot) {
                acc2[0][ot] = __builtin_amdgcn_mfma_f32_16x16x32_bf16(A0, wf[ot][ks], acc2[0][ot], 0, 0, 0);
                acc2[1][ot] = __builtin_amdgcn_mfma_f32_16x16x32_bf16(A1, wf[ot][ks], acc2[1][ot], 0, 0, 0);
            }
        }
        if (tl < 2) stx_fb(xsb, slot, pf, tid);

        const int t = t0 + tl;
#pragma unroll
        for (int ot = 0; ot < 2; ++ot) {
            const int o = (2 * wid + ot) * 16 + lam;
            float* op = out + ((size_t)(n * 192 + o) * 300 + t) * 25;
#pragma unroll
            for (int r = 0; r < 4; ++r) {
                float vv = acc2[0][ot][r] + bb[ot];
                op[cb + r] = vv > 0.f ? vv : 0.f;
            }
#pragma unroll
            for (int r = 0; r < 4; ++r) {
                const int tv = 16 + cb + r;
                if (tv < 25) {
                    float vv = acc2[1][ot][r] + bb[ot];
                    op[tv] = vv > 0.f ? vv : 0.f;
                }
            }
        }
    }
}

// ---------------------------------------------------------------------------
extern "C" void kernel_launch(void* const* d_in, const int* in_sizes, int n_in,
                              void* d_out, int out_size, void* d_ws, size_t ws_size,
                              hipStream_t stream) {
    const float* x     = (const float*)d_in[0];
    const float* xx    = (const float*)d_in[1];
    const float* A_res = (const float*)d_in[2];
    const float* W     = (const float*)d_in[3];
    const float* b     = (const float*)d_in[4];
    const float* gamma = (const float*)d_in[5];
    const float* beta  = (const float*)d_in[6];
    const float* rm    = (const float*)d_in[7];
    const float* rv    = (const float*)d_in[8];
    float* out = (float*)d_out;

    char* ws = (char*)d_ws;
    float* At_part  = (float*)ws;                    // 400000 B
    float* Acontrib = (float*)(ws + 400000);         //  80000 B
    short* bsTg     = (short*)(ws + 480000);         //   9216 B
    short* Wpg      = (short*)(ws + 489216);         //  73728 B
    float* bbg      = (float*)(ws + 562944);         //    768 B
    short* Wfrag    = (short*)(ws + 563712);         //  73728 B -> ends 637440
    short* agg2     = (short*)(ws + 637440);         // 92160000 B (PATH A only)
    const bool bigws = ws_size >= (size_t)637440 + 92160000u;

    kA<<<dim3(5, 32), 256, 0, stream>>>(xx, At_part);
    kB1<<<32, 256, 0, stream>>>(At_part, Acontrib);
    kB2<<<37, 256, 0, stream>>>(Acontrib, A_res, W, b, gamma, beta, rm, rv, bsTg, Wpg, bbg);
    kB2b<<<18, 256, 0, stream>>>(W, gamma, rv, Wfrag);

    if (bigws) {
        kC1<<<dim3(15, 32), 384, 0, stream>>>(x, bsTg, agg2);
        kC2<<<dim3(118, 32), 256, 0, stream>>>(agg2, Wfrag, bbg, out);
    } else {
        kC<<<dim3(75, 32), 384, 0, stream>>>(x, Wpg, bsTg, bbg, out);
    }
}

// Round 19
// 166.993 us; speedup vs baseline: 1.4168x; 1.1193x over previous
//
#include <hip/hip_runtime.h>
#include <hip/hip_bf16.h>

typedef __attribute__((ext_vector_type(8))) short short8;
typedef __attribute__((ext_vector_type(4))) short short4v;
typedef __attribute__((ext_vector_type(4))) float f32x4;
typedef __attribute__((ext_vector_type(2))) float f32x2;
typedef __attribute__((ext_vector_type(2))) unsigned int u32x2;

__device__ __forceinline__ unsigned short f2bf(float f) {
    unsigned int u = __builtin_bit_cast(unsigned int, f);
    u += 0x7fffu + ((u >> 16) & 1u);   // round-to-nearest-even
    return (unsigned short)(u >> 16);
}
__device__ __forceinline__ unsigned int pack2(float a, float b) {
    union { __hip_bfloat162 h; unsigned int u; } r;
    r.h = __float22bfloat162_rn(make_float2(a, b));
    return r.u;
}
__device__ __forceinline__ short4v cvt4(float a, float b, float c, float d) {
    union { __hip_bfloat162 h[2]; short4v s; } u;
    u.h[0] = __float22bfloat162_rn(make_float2(a, b));
    u.h[1] = __float22bfloat162_rn(make_float2(c, d));
    return u.s;
}

// ---------------------------------------------------------------------------
// Kernel A: partial adjacency sums over 60-frame chunks. grid (5,32).
// ---------------------------------------------------------------------------
__global__ void kA(const float* __restrict__ xx, float* __restrict__ At_part) {
    __shared__ float xs3[3][60][25];
    const int tc = blockIdx.x, n = blockIdx.y;
    const int tid = threadIdx.x;
    const float* base = xx + (size_t)n * 22500 + tc * 1500;
    for (int idx = tid; idx < 4500; idx += 256) {
        int ch = idx / 1500, rt = idx % 1500;
        xs3[ch][rt / 25][rt % 25] = base[ch * 7500 + rt];
    }
    __syncthreads();
    for (int p = tid; p < 625; p += 256) {
        int v = p / 25, u = p % 25;
        float s = 0.f;
        for (int t = 0; t < 60; ++t) {
            float dx = xs3[0][t][v] - xs3[0][t][u];
            float dy = xs3[1][t][v] - xs3[1][t][u];
            float dz = xs3[2][t][v] - xs3[2][t][u];
            s += __expf(-2.f * (dx * dx + dy * dy + dz * dz));
        }
        At_part[(size_t)(n * 5 + tc) * 625 + p] = s;
    }
}

// ---------------------------------------------------------------------------
// Kernel B1: per-sample reduce + symmetric normalization. grid 32.
// ---------------------------------------------------------------------------
__global__ void kB1(const float* __restrict__ At_part, float* __restrict__ Acontrib) {
    __shared__ float At[625];
    __shared__ float dinv[25];
    const int n = blockIdx.x, tid = threadIdx.x;
    for (int p = tid; p < 625; p += 256) {
        float s = 0.f;
        for (int tc = 0; tc < 5; ++tc) s += At_part[(size_t)(n * 5 + tc) * 625 + p];
        At[p] = s;
    }
    __syncthreads();
    if (tid < 25) {
        float d = 0.f;
        for (int u = 0; u < 25; ++u) d += At[tid * 25 + u];
        dinv[tid] = rsqrtf(d * (1.f / 300.f));
    }
    __syncthreads();
    for (int p = tid; p < 625; p += 256)
        Acontrib[n * 625 + p] = At[p] * (1.f / 300.f) * dinv[p / 25] * dinv[p % 25] * (1.f / 32.f);
}

// ---------------------------------------------------------------------------
// Kernel B2: block 0 -> bsTg (bf16 [64][72], zero-padded) + fused bias;
//            blocks 1..36 -> W'' = W * bn_scale  (layout [o][k], row-major).
// ---------------------------------------------------------------------------
__global__ void kB2(const float* __restrict__ Acontrib, const float* __restrict__ A_res,
                    const float* __restrict__ W, const float* __restrict__ b,
                    const float* __restrict__ gamma, const float* __restrict__ beta,
                    const float* __restrict__ rm, const float* __restrict__ rv,
                    short* __restrict__ bsTg, short* __restrict__ Wpg,
                    float* __restrict__ bbg) {
    const int tid = threadIdx.x;
    if (blockIdx.x == 0) {
        __shared__ float macc[625];
        for (int p = tid; p < 625; p += 256) {
            float s = 0.f;
            for (int n = 0; n < 32; ++n) s += Acontrib[n * 625 + p];
            macc[p] = s;
        }
        __syncthreads();
        for (int idx = tid; idx < 64 * 72; idx += 256) {
            int col = idx / 72, u = idx % 72;
            float v = 0.f;
            if (col < 50 && u < 50) v = macc[(col % 25) * 25 + (u % 25)] + A_res[col * 50 + u];
            bsTg[idx] = (short)f2bf(v);
        }
        if (tid < 192) {
            float sc = gamma[tid] * rsqrtf(rv[tid] + 1e-5f);
            bbg[tid] = b[tid] * sc + beta[tid] - rm[tid] * sc;
        }
    } else {
        const int e = (blockIdx.x - 1) * 1024 + tid * 4;
        const int o = e / 192;
        const float sc = gamma[o] * rsqrtf(rv[o] + 1e-5f);
        float4 w = *(const float4*)(W + e);
        short4v s4 = { (short)f2bf(w.x * sc), (short)f2bf(w.y * sc),
                       (short)f2bf(w.z * sc), (short)f2bf(w.w * sc) };
        *(short4v*)(Wpg + e) = s4;
    }
}

// ---------------------------------------------------------------------------
// Kernel B2b: W'' in MFMA-fragment order for kC2's coalesced wf loads.
// ---------------------------------------------------------------------------
__global__ void kB2b(const float* __restrict__ W, const float* __restrict__ gamma,
                     const float* __restrict__ rv, short* __restrict__ Wfrag) {
    const int idx = blockIdx.x * 256 + threadIdx.x;     // < 4608
    const int ot = idx / 384, r = idx - ot * 384;
    const int ks = r / 64, lane = r - ks * 64;
    const int o = ot * 16 + (lane & 15);
    const int k0 = ks * 32 + (lane >> 4) * 8;
    const float sc = gamma[o] * rsqrtf(rv[o] + 1e-5f);
    float4 w0 = *(const float4*)(W + o * 192 + k0);
    float4 w1 = *(const float4*)(W + o * 192 + k0 + 4);
    union { short4v h[2]; short8 v; } u;
    u.h[0] = cvt4(w0.x * sc, w0.y * sc, w0.z * sc, w0.w * sc);
    u.h[1] = cvt4(w1.x * sc, w1.y * sc, w1.z * sc, w1.w * sc);
    *(short8*)(Wfrag + (size_t)idx * 8) = u.v;
}

// ---------------------------------------------------------------------------
// PATH A kernel 1 (exact R13, best measured): GEMM1 -> agg2[n][tv][k] bf16.
// grid (15,32)=480 blocks ~ 2-blk/CU residency -> ONE block-round.
// 20 timesteps/block; stage/dump addresses precomputed (t-invariant);
// coalesced stage -> banked-LDS transpose -> coalesced dwordx2 dump;
// ONE lgkm+barrier per timestep; double-buffered xsb/a2T.
// ---------------------------------------------------------------------------
__global__ __launch_bounds__(384, 3)
void kC1(const float* __restrict__ x, const short* __restrict__ bsTg,
         short* __restrict__ agg2) {
    __shared__ __align__(16) char xsb[2 * 12288];
    __shared__ __align__(16) short bsT[64 * 72];
    __shared__ __align__(16) short a2T[2][32][208];

    const int tid = threadIdx.x;
    const int lane = tid & 63;
    const int wid = tid >> 6;
    const int lam = lane & 15;
    const int kc = (lane >> 4) * 8;
    const int cb = (lane >> 4) * 4;
    const int n = blockIdx.y;
    const int t0 = blockIdx.x * 20;
    const int gb0 = n * 1440000 + t0 * 50;
    const int cgl = wid * 16 + lam;

    // ---- t-invariant per-thread offsets ----
    int goff[7], loff[7];
#pragma unroll
    for (int i = 0; i < 7; ++i) {
        int idx = i * 384 + tid;
        int idc = idx < 2400 ? idx : 2399;
        int c = idc / 25, q = idc - c * 25;
        goff[i] = c * 15000 + 2 * q;
        loff[i] = (c * 128 + q * 4) ^ ((c & 7) << 4);
    }
    int asrc[4];
#pragma unroll
    for (int i = 0; i < 4; ++i) {
        int idx = i * 768 + tid * 2;               // dwordx2 pairs, 96 | 768
        int idc = idx < 2400 ? idx : 2398;
        asrc[i] = idc + (idc / 96) * 8;            // a2T row stride 104 dwords
    }

    // ---- prologue: stage t0 -> slot0, t1 -> slot1 ----
    f32x2 pf2[13];
#pragma unroll
    for (int i = 0; i < 13; ++i) {
        int idx = i * 384 + tid;
        idx = idx < 4800 ? idx : 4799;
        int c = idx / 50, q2 = idx - c * 50;
        int tl = q2 >= 25, q = q2 - 25 * tl;
        pf2[i] = *(const f32x2*)(x + gb0 + c * 15000 + tl * 50 + 2 * q);
    }
    {
        const int4* src = (const int4*)bsTg;
        int4* dst = (int4*)bsT;
        for (int i = tid; i < 576; i += 384) dst[i] = src[i];
    }
    for (int idx = tid; idx < 1344; idx += 384) {
        int r = idx / 7, k = idx - r * 7;
        int slot = r / 96, c = r - 96 * slot;
        *(unsigned int*)(xsb + ((slot * 12288 + c * 128 + (50 + 2 * k) * 2) ^ ((c & 7) << 4))) = 0;
    }
#pragma unroll
    for (int i = 0; i < 13; ++i) {
        int idx = i * 384 + tid;
        if (idx < 4800) {
            int c = idx / 50, q2 = idx - c * 50;
            int tl = q2 >= 25, q = q2 - 25 * tl;
            *(unsigned int*)(xsb + ((tl * 12288 + c * 128 + q * 4) ^ ((c & 7) << 4)))
                = pack2(pf2[i].x, pf2[i].y);
        }
    }
    asm volatile("s_waitcnt lgkmcnt(0)" ::: "memory");
    __builtin_amdgcn_s_barrier();

    const f32x4 z = {0.f, 0.f, 0.f, 0.f};
    f32x2 pf[7];

#pragma unroll 1
    for (int tl = 0; tl < 20; ++tl) {
        const int slot = tl & 1;
        short* a2w = &a2T[slot][0][0];

        // issue t+2 loads early (precomputed addresses)
        if (tl < 18) {
            const float* xb2 = x + gb0 + (tl + 2) * 50;
#pragma unroll
            for (int i = 0; i < 7; ++i)
                if (i < 6 || tid < 96) pf[i] = *(const f32x2*)(xb2 + goff[i]);
        }

        // ---- GEMM1 ----
        short8 xb[2];
#pragma unroll
        for (int ks = 0; ks < 2; ++ks)
            xb[ks] = *(const short8*)(xsb +
                ((slot * 12288 + cgl * 128 + (ks * 32 + kc) * 2) ^ ((cgl & 7) << 4)));
        f32x4 acc1[4];
#pragma unroll
        for (int m = 0; m < 4; ++m) acc1[m] = z;
#pragma unroll
        for (int ks = 0; ks < 2; ++ks)
#pragma unroll
            for (int m = 0; m < 4; ++m) {
                const short8 af = *(const short8*)(bsT + (m * 16 + lam) * 72 + ks * 32 + kc);
                acc1[m] = __builtin_amdgcn_mfma_f32_16x16x32_bf16(af, xb[ks], acc1[m], 0, 0, 0);
            }

        // scatter -> a2T[slot]
#pragma unroll
        for (int m = 0; m < 3; ++m) {
            short4v sv = cvt4(acc1[m][0], acc1[m][1], acc1[m][2], acc1[m][3]);
#pragma unroll
            for (int r = 0; r < 4; ++r) {
                const int v = m * 16 + cb + r;
                const int s = v >= 25;
                a2w[(v - 25 * s) * 208 + s * 96 + cgl] = sv[r];
            }
        }
        if (cb == 0) {
            a2w[23 * 208 + 96 + cgl] = (short)f2bf(acc1[3][0]);
            a2w[24 * 208 + 96 + cgl] = (short)f2bf(acc1[3][1]);
        }
        asm volatile("s_waitcnt lgkmcnt(0)" ::: "memory");
        __builtin_amdgcn_s_barrier();

        // ---- dump a2T[slot] -> agg2 (paired dwordx2, coalesced) ----
        {
            const unsigned int* a2d = (const unsigned int*)a2w;
            unsigned int* dst = (unsigned int*)agg2
                + (size_t)n * 720000 + (size_t)(t0 + tl) * 2400;
#pragma unroll
            for (int i = 0; i < 4; ++i) {
                int idx = i * 768 + tid * 2;
                if (i < 3 || tid < 48) {
                    u32x2 v;
                    v.x = a2d[asrc[i]];
                    v.y = a2d[asrc[i] + 1];
                    *(u32x2*)(dst + idx) = v;
                }
            }
        }

        // write t+2 into freed slot
        if (tl < 18) {
            char* xw = xsb + slot * 12288;
#pragma unroll
            for (int i = 0; i < 7; ++i)
                if (i < 6 || tid < 96)
                    *(unsigned int*)(xw + loff[i]) = pack2(pf[i].x, pf[i].y);
        }
        // no trailing barrier: double-buffered a2T/xsb; next iter's barrier
        // (after lgkmcnt(0)) orders these LDS writes before their reads.
    }
}

// ---------------------------------------------------------------------------
// PATH A kernel 2 (verbatim R12, proven ~60us): out = ReLU(W''@agg2 + bias).
// grid (118,32) x 256 thr; contiguous tile stage; coalesced wf; float4 stores.
// ---------------------------------------------------------------------------
__global__ __launch_bounds__(256, 3)
void kC2(const short* __restrict__ agg2, const short* __restrict__ Wfrag,
         const float* __restrict__ bbg, float* __restrict__ out) {
    __shared__ __align__(16) unsigned int asb[64 * 100];

    const int tid = threadIdx.x;
    const int lane = tid & 63;
    const int wid = tid >> 6;
    const int lam = lane & 15;
    const int kc = (lane >> 4) * 8;
    const int cb = (lane >> 4) * 4;
    const int n = blockIdx.y;
    const int tv0 = blockIdx.x * 64;

    short8 wf[3][6];
    float bb[3];
#pragma unroll
    for (int j = 0; j < 3; ++j) {
        const int ot = wid * 3 + j;
#pragma unroll
        for (int ks = 0; ks < 6; ++ks)
            wf[j][ks] = *(const short8*)(Wfrag + ((size_t)(ot * 6 + ks) * 64 + lane) * 8);
        bb[j] = bbg[ot * 16 + lam];
    }

    {
        const unsigned int* src = (const unsigned int*)agg2 + (size_t)n * 720000;
#pragma unroll
        for (int k = 0; k < 24; ++k) {
            int d = k * 256 + tid;
            int row = d / 96, c2 = d - row * 96;
            int tvg = tv0 + row;
            tvg = tvg < 7500 ? tvg : 7499;
            asb[row * 100 + c2] = src[(size_t)tvg * 96 + c2];
        }
    }
    __syncthreads();

    const f32x4 z = {0.f, 0.f, 0.f, 0.f};
    f32x4 acc[4][3];
#pragma unroll
    for (int m = 0; m < 4; ++m)
#pragma unroll
        for (int j = 0; j < 3; ++j) acc[m][j] = z;

#pragma unroll
    for (int ks = 0; ks < 6; ++ks) {
        short8 a[4];
#pragma unroll
        for (int m = 0; m < 4; ++m)
            a[m] = *(const short8*)((const short*)asb + (m * 16 + lam) * 200 + ks * 32 + kc);
#pragma unroll
        for (int m = 0; m < 4; ++m)
#pragma unroll
            for (int j = 0; j < 3; ++j)
                acc[m][j] = __builtin_amdgcn_mfma_f32_16x16x32_bf16(a[m], wf[j][ks], acc[m][j], 0, 0, 0);
    }

#pragma unroll
    for (int m = 0; m < 4; ++m) {
        const int tvg = tv0 + m * 16 + cb;
        if (tvg < 7500) {
#pragma unroll
            for (int j = 0; j < 3; ++j) {
                const int o = (wid * 3 + j) * 16 + lam;
                float4 v;
                v.x = acc[m][j][0] + bb[j]; v.x = v.x > 0.f ? v.x : 0.f;
                v.y = acc[m][j][1] + bb[j]; v.y = v.y > 0.f ? v.y : 0.f;
                v.z = acc[m][j][2] + bb[j]; v.z = v.z > 0.f ? v.z : 0.f;
                v.w = acc[m][j][3] + bb[j]; v.w = v.w > 0.f ? v.w : 0.f;
                *(float4*)(out + (size_t)(n * 192 + o) * 7500 + tvg) = v;
            }
        }
    }
}

// ---------------------------------------------------------------------------
// PATH B fallback (== R11 fused kernel), used when ws is too small.
// ---------------------------------------------------------------------------
__device__ __forceinline__ void ldx_fb(const float* __restrict__ x, int gbase,
                                       f32x2 (&pf)[7], int tid) {
#pragma unroll
    for (int i = 0; i < 7; ++i) {
        int idx = i * 384 + tid;
        idx = idx < 2400 ? idx : 2399;
        int c = idx / 25, q = idx - c * 25;
        pf[i] = *(const f32x2*)(x + gbase + c * 15000 + 2 * q);
    }
}
__device__ __forceinline__ void stx_fb(char* xsb, int slot, const f32x2 (&pf)[7], int tid) {
#pragma unroll
    for (int i = 0; i < 7; ++i) {
        int idx = i * 384 + tid;
        if (idx < 2400) {
            int c = idx / 25, q = idx - c * 25;
            *(unsigned int*)(xsb + ((slot * 12288 + c * 128 + q * 4) ^ ((c & 7) << 4)))
                = pack2(pf[i].x, pf[i].y);
        }
    }
}

__global__ __launch_bounds__(384, 3)
void kC(const float* __restrict__ x, const short* __restrict__ Wpg,
        const short* __restrict__ bsTg, const float* __restrict__ bbg,
        float* __restrict__ out) {
    __shared__ __align__(16) char xsb[2 * 12288];
    __shared__ __align__(16) short bsT[64 * 72];
    __shared__ __align__(16) short a2T[2][32][208];

    const int tid = threadIdx.x;
    const int lane = tid & 63;
    const int wid = tid >> 6;
    const int lam = lane & 15;
    const int kc = (lane >> 4) * 8;
    const int cb = (lane >> 4) * 4;
    const int n = blockIdx.y;
    const int t0 = blockIdx.x * 4;
    const int gb0 = n * 1440000 + t0 * 50;
    const int cgl = wid * 16 + lam;

    f32x2 pf2[13];
#pragma unroll
    for (int i = 0; i < 13; ++i) {
        int idx = i * 384 + tid;
        idx = idx < 4800 ? idx : 4799;
        int c = idx / 50, q2 = idx - c * 50;
        int tl = q2 >= 25, q = q2 - 25 * tl;
        pf2[i] = *(const f32x2*)(x + gb0 + c * 15000 + tl * 50 + 2 * q);
    }
    short8 wf[2][6];
#pragma unroll
    for (int ot = 0; ot < 2; ++ot)
#pragma unroll
        for (int ks = 0; ks < 6; ++ks)
            wf[ot][ks] = *(const short8*)(Wpg + ((2 * wid + ot) * 16 + lam) * 192 + ks * 32 + kc);
    float bb[2];
#pragma unroll
    for (int ot = 0; ot < 2; ++ot) bb[ot] = bbg[(2 * wid + ot) * 16 + lam];
    {
        const int4* src = (const int4*)bsTg;
        int4* dst = (int4*)bsT;
        for (int i = tid; i < 576; i += 384) dst[i] = src[i];
    }
    for (int idx = tid; idx < 1344; idx += 384) {
        int r = idx / 7, k = idx - r * 7;
        int slot = r / 96, c = r - 96 * slot;
        *(unsigned int*)(xsb + ((slot * 12288 + c * 128 + (50 + 2 * k) * 2) ^ ((c & 7) << 4))) = 0;
    }
    for (int idx = tid; idx < 1456; idx += 384) {
        int buf = idx / 728, rem = idx - buf * 728;
        int row = 25 + rem / 104, col2 = rem - (rem / 104) * 104;
        *((unsigned int*)&a2T[buf][row][0] + col2) = 0;
    }
#pragma unroll
    for (int i = 0; i < 13; ++i) {
        int idx = i * 384 + tid;
        if (idx < 4800) {
            int c = idx / 50, q2 = idx - c * 50;
            int tl = q2 >= 25, q = q2 - 25 * tl;
            *(unsigned int*)(xsb + ((tl * 12288 + c * 128 + q * 4) ^ ((c & 7) << 4)))
                = pack2(pf2[i].x, pf2[i].y);
        }
    }
    asm volatile("s_waitcnt lgkmcnt(0)" ::: "memory");
    __builtin_amdgcn_s_barrier();

    const f32x4 z = {0.f, 0.f, 0.f, 0.f};
    f32x2 pf[7];

#pragma unroll 1
    for (int tl = 0; tl < 4; ++tl) {
        const int slot = tl & 1;
        short* a2w = &a2T[slot][0][0];
        if (tl < 2) ldx_fb(x, gb0 + (tl + 2) * 50, pf, tid);

        short8 xb[2];
#pragma unroll
        for (int ks = 0; ks < 2; ++ks)
            xb[ks] = *(const short8*)(xsb +
                ((slot * 12288 + cgl * 128 + (ks * 32 + kc) * 2) ^ ((cgl & 7) << 4)));
        f32x4 acc1[4];
#pragma unroll
        for (int m = 0; m < 4; ++m) acc1[m] = z;
#pragma unroll
        for (int ks = 0; ks < 2; ++ks)
#pragma unroll
            for (int m = 0; m < 4; ++m) {
                const short8 af = *(const short8*)(bsT + (m * 16 + lam) * 72 + ks * 32 + kc);
                acc1[m] = __builtin_amdgcn_mfma_f32_16x16x32_bf16(af, xb[ks], acc1[m], 0, 0, 0);
            }
#pragma unroll
        for (int m = 0; m < 3; ++m) {
            short4v sv = cvt4(acc1[m][0], acc1[m][1], acc1[m][2], acc1[m][3]);
#pragma unroll
            for (int r = 0; r < 4; ++r) {
                const int v = m * 16 + cb + r;
                const int s = v >= 25;
                a2w[(v - 25 * s) * 208 + s * 96 + cgl] = sv[r];
            }
        }
        if (cb == 0) {
            a2w[23 * 208 + 96 + cgl] = (short)f2bf(acc1[3][0]);
            a2w[24 * 208 + 96 + cgl] = (short)f2bf(acc1[3][1]);
        }
        asm volatile("s_waitcnt lgkmcnt(0)" ::: "memory");
        __builtin_amdgcn_s_barrier();

        f32x4 acc2[2][2];
#pragma unroll
        for (int g = 0; g < 2; ++g) { acc2[g][0] = z; acc2[g][1] = z; }
#pragma unroll
        for (int ks = 0; ks < 6; ++ks) {
            const short8 A0 = *(const short8*)(a2w + lam * 208 + ks * 32 + kc);
            const short8 A1 = *(const short8*)(a2w + (16 + lam) * 208 + ks * 32 + kc);
#pragma unroll
            for (int ot = 0; ot < 2; ++ot) {
                acc2[0][ot] = __builtin_amdgcn_mfma_f32_16x16x32_bf16(A0, wf[ot][ks], acc2[0][ot], 0, 0, 0);
                acc2[1][ot] = __builtin_amdgcn_mfma_f32_16x16x32_bf16(A1, wf[ot][ks], acc2[1][ot], 0, 0, 0);
            }
        }
        if (tl < 2) stx_fb(xsb, slot, pf, tid);

        const int t = t0 + tl;
#pragma unroll
        for (int ot = 0; ot < 2; ++ot) {
            const int o = (2 * wid + ot) * 16 + lam;
            float* op = out + ((size_t)(n * 192 + o) * 300 + t) * 25;
#pragma unroll
            for (int r = 0; r < 4; ++r) {
                float vv = acc2[0][ot][r] + bb[ot];
                op[cb + r] = vv > 0.f ? vv : 0.f;
            }
#pragma unroll
            for (int r = 0; r < 4; ++r) {
                const int tv = 16 + cb + r;
                if (tv < 25) {
                    float vv = acc2[1][ot][r] + bb[ot];
                    op[tv] = vv > 0.f ? vv : 0.f;
                }
            }
        }
    }
}

// ---------------------------------------------------------------------------
extern "C" void kernel_launch(void* const* d_in, const int* in_sizes, int n_in,
                              void* d_out, int out_size, void* d_ws, size_t ws_size,
                              hipStream_t stream) {
    const float* x     = (const float*)d_in[0];
    const float* xx    = (const float*)d_in[1];
    const float* A_res = (const float*)d_in[2];
    const float* W     = (const float*)d_in[3];
    const float* b     = (const float*)d_in[4];
    const float* gamma = (const float*)d_in[5];
    const float* beta  = (const float*)d_in[6];
    const float* rm    = (const float*)d_in[7];
    const float* rv    = (const float*)d_in[8];
    float* out = (float*)d_out;

    char* ws = (char*)d_ws;
    float* At_part  = (float*)ws;                    // 400000 B
    float* Acontrib = (float*)(ws + 400000);         //  80000 B
    short* bsTg     = (short*)(ws + 480000);         //   9216 B
    short* Wpg      = (short*)(ws + 489216);         //  73728 B
    float* bbg      = (float*)(ws + 562944);         //    768 B
    short* Wfrag    = (short*)(ws + 563712);         //  73728 B -> ends 637440
    short* agg2     = (short*)(ws + 637440);         // 92160000 B (PATH A only)
    const bool bigws = ws_size >= (size_t)637440 + 92160000u;

    kA<<<dim3(5, 32), 256, 0, stream>>>(xx, At_part);
    kB1<<<32, 256, 0, stream>>>(At_part, Acontrib);
    kB2<<<37, 256, 0, stream>>>(Acontrib, A_res, W, b, gamma, beta, rm, rv, bsTg, Wpg, bbg);
    kB2b<<<18, 256, 0, stream>>>(W, gamma, rv, Wfrag);

    if (bigws) {
        kC1<<<dim3(15, 32), 384, 0, stream>>>(x, bsTg, agg2);
        kC2<<<dim3(118, 32), 256, 0, stream>>>(agg2, Wfrag, bbg, out);
    } else {
        kC<<<dim3(75, 32), 384, 0, stream>>>(x, Wpg, bsTg, bbg, out);
    }
}

// Round 20
// 158.505 us; speedup vs baseline: 1.4927x; 1.0535x over previous
//
#include <hip/hip_runtime.h>
#include <hip/hip_bf16.h>

typedef __attribute__((ext_vector_type(8))) short short8;
typedef __attribute__((ext_vector_type(4))) short short4v;
typedef __attribute__((ext_vector_type(4))) float f32x4;
typedef __attribute__((ext_vector_type(2))) float f32x2;

__device__ __forceinline__ unsigned short f2bf(float f) {
    unsigned int u = __builtin_bit_cast(unsigned int, f);
    u += 0x7fffu + ((u >> 16) & 1u);   // round-to-nearest-even
    return (unsigned short)(u >> 16);
}
__device__ __forceinline__ unsigned int pack2(float a, float b) {
    union { __hip_bfloat162 h; unsigned int u; } r;
    r.h = __float22bfloat162_rn(make_float2(a, b));
    return r.u;
}
__device__ __forceinline__ short4v cvt4(float a, float b, float c, float d) {
    union { __hip_bfloat162 h[2]; short4v s; } u;
    u.h[0] = __float22bfloat162_rn(make_float2(a, b));
    u.h[1] = __float22bfloat162_rn(make_float2(c, d));
    return u.s;
}

// ---------------------------------------------------------------------------
// Kernel A: partial adjacency sums over 60-frame chunks. grid (5,32).
// ---------------------------------------------------------------------------
__global__ void kA(const float* __restrict__ xx, float* __restrict__ At_part) {
    __shared__ float xs3[3][60][25];
    const int tc = blockIdx.x, n = blockIdx.y;
    const int tid = threadIdx.x;
    const float* base = xx + (size_t)n * 22500 + tc * 1500;
    for (int idx = tid; idx < 4500; idx += 256) {
        int ch = idx / 1500, rt = idx % 1500;
        xs3[ch][rt / 25][rt % 25] = base[ch * 7500 + rt];
    }
    __syncthreads();
    for (int p = tid; p < 625; p += 256) {
        int v = p / 25, u = p % 25;
        float s = 0.f;
        for (int t = 0; t < 60; ++t) {
            float dx = xs3[0][t][v] - xs3[0][t][u];
            float dy = xs3[1][t][v] - xs3[1][t][u];
            float dz = xs3[2][t][v] - xs3[2][t][u];
            s += __expf(-2.f * (dx * dx + dy * dy + dz * dz));
        }
        At_part[(size_t)(n * 5 + tc) * 625 + p] = s;
    }
}

// ---------------------------------------------------------------------------
// Kernel B1: per-sample reduce + symmetric normalization. grid 32.
// ---------------------------------------------------------------------------
__global__ void kB1(const float* __restrict__ At_part, float* __restrict__ Acontrib) {
    __shared__ float At[625];
    __shared__ float dinv[25];
    const int n = blockIdx.x, tid = threadIdx.x;
    for (int p = tid; p < 625; p += 256) {
        float s = 0.f;
        for (int tc = 0; tc < 5; ++tc) s += At_part[(size_t)(n * 5 + tc) * 625 + p];
        At[p] = s;
    }
    __syncthreads();
    if (tid < 25) {
        float d = 0.f;
        for (int u = 0; u < 25; ++u) d += At[tid * 25 + u];
        dinv[tid] = rsqrtf(d * (1.f / 300.f));
    }
    __syncthreads();
    for (int p = tid; p < 625; p += 256)
        Acontrib[n * 625 + p] = At[p] * (1.f / 300.f) * dinv[p / 25] * dinv[p % 25] * (1.f / 32.f);
}

// ---------------------------------------------------------------------------
// Kernel B2: block 0 -> bsTg (bf16 [64][72], zero-padded) + fused bias;
//            blocks 1..36 -> W'' = W * bn_scale  (layout [o][k], row-major).
// ---------------------------------------------------------------------------
__global__ void kB2(const float* __restrict__ Acontrib, const float* __restrict__ A_res,
                    const float* __restrict__ W, const float* __restrict__ b,
                    const float* __restrict__ gamma, const float* __restrict__ beta,
                    const float* __restrict__ rm, const float* __restrict__ rv,
                    short* __restrict__ bsTg, short* __restrict__ Wpg,
                    float* __restrict__ bbg) {
    const int tid = threadIdx.x;
    if (blockIdx.x == 0) {
        __shared__ float macc[625];
        for (int p = tid; p < 625; p += 256) {
            float s = 0.f;
            for (int n = 0; n < 32; ++n) s += Acontrib[n * 625 + p];
            macc[p] = s;
        }
        __syncthreads();
        for (int idx = tid; idx < 64 * 72; idx += 256) {
            int col = idx / 72, u = idx % 72;
            float v = 0.f;
            if (col < 50 && u < 50) v = macc[(col % 25) * 25 + (u % 25)] + A_res[col * 50 + u];
            bsTg[idx] = (short)f2bf(v);
        }
        if (tid < 192) {
            float sc = gamma[tid] * rsqrtf(rv[tid] + 1e-5f);
            bbg[tid] = b[tid] * sc + beta[tid] - rm[tid] * sc;
        }
    } else {
        const int e = (blockIdx.x - 1) * 1024 + tid * 4;
        const int o = e / 192;
        const float sc = gamma[o] * rsqrtf(rv[o] + 1e-5f);
        float4 w = *(const float4*)(W + e);
        short4v s4 = { (short)f2bf(w.x * sc), (short)f2bf(w.y * sc),
                       (short)f2bf(w.z * sc), (short)f2bf(w.w * sc) };
        *(short4v*)(Wpg + e) = s4;
    }
}

// ---------------------------------------------------------------------------
// Fused kernel kCf: graph-conv + 1x1 conv + BN + ReLU, no intermediate.
// grid (15,32)=480 blocks (~2/CU residency, ONE round), 384 thr = 6 waves,
// TC=20 timesteps/block.  Per t (ONE lgkm+barrier):
//   pf loads(t+2) -> GEMM1 (bsT LDS + xsb slot) -> scatter a2T[slot]
//   -> lgkm+barrier -> GEMM2 (a2T + wf regs) -> out stores -> stx(t+2).
// LDS: xsb 24.6K + bsT 9.2K + a2T dbuf 26.6K = 60.4 KB; regs ~130 @(384,3).
// ---------------------------------------------------------------------------
#define TCF 20
__global__ __launch_bounds__(384, 3)
void kCf(const float* __restrict__ x, const short* __restrict__ Wpg,
         const short* __restrict__ bsTg, const float* __restrict__ bbg,
         float* __restrict__ out) {
    __shared__ __align__(16) char xsb[2 * 12288];
    __shared__ __align__(16) short bsT[64 * 72];
    __shared__ __align__(16) short a2T[2][32][208];

    const int tid = threadIdx.x;
    const int lane = tid & 63;
    const int wid = tid >> 6;          // 0..5
    const int lam = lane & 15;
    const int kc = (lane >> 4) * 8;
    const int cb = (lane >> 4) * 4;
    const int n = blockIdx.y;
    const int t0 = blockIdx.x * TCF;
    const int gb0 = n * 1440000 + t0 * 50;
    const int cgl = wid * 16 + lam;

    // ---- t-invariant per-thread stage offsets ----
    int goff[7], loff[7];
#pragma unroll
    for (int i = 0; i < 7; ++i) {
        int idx = i * 384 + tid;
        int idc = idx < 2400 ? idx : 2399;
        int c = idc / 25, q = idc - c * 25;
        goff[i] = c * 15000 + 2 * q;
        loff[i] = (c * 128 + q * 4) ^ ((c & 7) << 4);
    }

    // W'' fragments in regs (GEMM2 B-operand: col o, k rows) + bias
    short8 wf[2][6];
#pragma unroll
    for (int ot = 0; ot < 2; ++ot)
#pragma unroll
        for (int ks = 0; ks < 6; ++ks)
            wf[ot][ks] = *(const short8*)(Wpg + ((2 * wid + ot) * 16 + lam) * 192 + ks * 32 + kc);
    float bb[2];
#pragma unroll
    for (int ot = 0; ot < 2; ++ot) bb[ot] = bbg[(2 * wid + ot) * 16 + lam];

    // ---- prologue ----
    f32x2 pf2[13];
#pragma unroll
    for (int i = 0; i < 13; ++i) {
        int idx = i * 384 + tid;
        idx = idx < 4800 ? idx : 4799;
        int c = idx / 50, q2 = idx - c * 50;
        int tl = q2 >= 25, q = q2 - 25 * tl;
        pf2[i] = *(const f32x2*)(x + gb0 + c * 15000 + tl * 50 + 2 * q);
    }
    {
        const int4* src = (const int4*)bsTg;
        int4* dst = (int4*)bsT;
        for (int i = tid; i < 576; i += 384) dst[i] = src[i];
    }
    // zero xsb u-pads (both slots)
    for (int idx = tid; idx < 1344; idx += 384) {
        int r = idx / 7, k = idx - r * 7;
        int slot = r / 96, c = r - 96 * slot;
        *(unsigned int*)(xsb + ((slot * 12288 + c * 128 + (50 + 2 * k) * 2) ^ ((c & 7) << 4))) = 0;
    }
    // zero a2T pad rows 25..31 (both buffers) -> GEMM2 A1 rows stay finite 0
    for (int idx = tid; idx < 1456; idx += 384) {
        int buf = idx / 728, rem = idx - buf * 728;
        int row = 25 + rem / 104, col2 = rem - (rem / 104) * 104;
        *((unsigned int*)&a2T[buf][row][0] + col2) = 0;
    }
    // write t0 -> slot0, t1 -> slot1
#pragma unroll
    for (int i = 0; i < 13; ++i) {
        int idx = i * 384 + tid;
        if (idx < 4800) {
            int c = idx / 50, q2 = idx - c * 50;
            int tl = q2 >= 25, q = q2 - 25 * tl;
            *(unsigned int*)(xsb + ((tl * 12288 + c * 128 + q * 4) ^ ((c & 7) << 4)))
                = pack2(pf2[i].x, pf2[i].y);
        }
    }
    asm volatile("s_waitcnt lgkmcnt(0)" ::: "memory");
    __builtin_amdgcn_s_barrier();

    const f32x4 z = {0.f, 0.f, 0.f, 0.f};
    f32x2 pf[7];

#pragma unroll 1
    for (int tl = 0; tl < TCF; ++tl) {
        const int slot = tl & 1;
        short* a2w = &a2T[slot][0][0];

        // issue t+2 coalesced loads early (precomputed addresses)
        if (tl < TCF - 2) {
            const float* xb2 = x + gb0 + (tl + 2) * 50;
#pragma unroll
            for (int i = 0; i < 7; ++i)
                if (i < 6 || tid < 96) pf[i] = *(const f32x2*)(xb2 + goff[i]);
        }

        // ---- GEMM1: D[v][c] (8 MFMA) ----
        short8 xb[2];
#pragma unroll
        for (int ks = 0; ks < 2; ++ks)
            xb[ks] = *(const short8*)(xsb +
                ((slot * 12288 + cgl * 128 + (ks * 32 + kc) * 2) ^ ((cgl & 7) << 4)));
        f32x4 acc1[4];
#pragma unroll
        for (int m = 0; m < 4; ++m) acc1[m] = z;
#pragma unroll
        for (int ks = 0; ks < 2; ++ks)
#pragma unroll
            for (int m = 0; m < 4; ++m) {
                const short8 af = *(const short8*)(bsT + (m * 16 + lam) * 72 + ks * 32 + kc);
                acc1[m] = __builtin_amdgcn_mfma_f32_16x16x32_bf16(af, xb[ks], acc1[m], 0, 0, 0);
            }

        // scatter agg -> a2T[slot][vs][s*96 + c]
#pragma unroll
        for (int m = 0; m < 3; ++m) {
            short4v sv = cvt4(acc1[m][0], acc1[m][1], acc1[m][2], acc1[m][3]);
#pragma unroll
            for (int r = 0; r < 4; ++r) {
                const int v = m * 16 + cb + r;
                const int s = v >= 25;
                a2w[(v - 25 * s) * 208 + s * 96 + cgl] = sv[r];
            }
        }
        if (cb == 0) {
            a2w[23 * 208 + 96 + cgl] = (short)f2bf(acc1[3][0]);
            a2w[24 * 208 + 96 + cgl] = (short)f2bf(acc1[3][1]);
        }
        asm volatile("s_waitcnt lgkmcnt(0)" ::: "memory");
        __builtin_amdgcn_s_barrier();   // a2T[slot] ready; all xb reads done

        // ---- GEMM2 (flipped): D[tv][o], W'' from registers (24 MFMA) ----
        f32x4 acc2[2][2];
#pragma unroll
        for (int g = 0; g < 2; ++g) { acc2[g][0] = z; acc2[g][1] = z; }
#pragma unroll
        for (int ks = 0; ks < 6; ++ks) {
            const short8 A0 = *(const short8*)(a2w + lam * 208 + ks * 32 + kc);
            const short8 A1 = *(const short8*)(a2w + (16 + lam) * 208 + ks * 32 + kc);
#pragma unroll
            for (int ot = 0; ot < 2; ++ot) {
                acc2[0][ot] = __builtin_amdgcn_mfma_f32_16x16x32_bf16(A0, wf[ot][ks], acc2[0][ot], 0, 0, 0);
                acc2[1][ot] = __builtin_amdgcn_mfma_f32_16x16x32_bf16(A1, wf[ot][ks], acc2[1][ot], 0, 0, 0);
            }
        }

        // ---- epilogue: ReLU(acc+bias), per-lane contiguous dwords ----
        const int t = t0 + tl;
#pragma unroll
        for (int ot = 0; ot < 2; ++ot) {
            const int o = (2 * wid + ot) * 16 + lam;
            float* op = out + ((size_t)(n * 192 + o) * 300 + t) * 25;
#pragma unroll
            for (int r = 0; r < 4; ++r) {               // tv = cb+r < 16
                float vv = acc2[0][ot][r] + bb[ot];
                op[cb + r] = vv > 0.f ? vv : 0.f;
            }
#pragma unroll
            for (int r = 0; r < 4; ++r) {               // tv = 16+cb+r
                const int tv = 16 + cb + r;
                if (tv < 25) {
                    float vv = acc2[1][ot][r] + bb[ot];
                    op[tv] = vv > 0.f ? vv : 0.f;
                }
            }
        }

        // write t+2 into the freed slot (all waves passed this t's barrier,
        // so their xb reads of this slot are complete and drained)
        if (tl < TCF - 2) {
            char* xw = xsb + slot * 12288;
#pragma unroll
            for (int i = 0; i < 7; ++i)
                if (i < 6 || tid < 96)
                    *(unsigned int*)(xw + loff[i]) = pack2(pf[i].x, pf[i].y);
        }
        // no trailing barrier: next iteration uses the OTHER xsb slot / a2T
        // buffer; its lgkm(0)+barrier orders these LDS writes before reads.
    }
}

// ---------------------------------------------------------------------------
extern "C" void kernel_launch(void* const* d_in, const int* in_sizes, int n_in,
                              void* d_out, int out_size, void* d_ws, size_t ws_size,
                              hipStream_t stream) {
    const float* x     = (const float*)d_in[0];
    const float* xx    = (const float*)d_in[1];
    const float* A_res = (const float*)d_in[2];
    const float* W     = (const float*)d_in[3];
    const float* b     = (const float*)d_in[4];
    const float* gamma = (const float*)d_in[5];
    const float* beta  = (const float*)d_in[6];
    const float* rm    = (const float*)d_in[7];
    const float* rv    = (const float*)d_in[8];
    float* out = (float*)d_out;

    char* ws = (char*)d_ws;
    float* At_part  = (float*)ws;                    // 400000 B
    float* Acontrib = (float*)(ws + 400000);         //  80000 B
    short* bsTg     = (short*)(ws + 480000);         //   9216 B
    short* Wpg      = (short*)(ws + 489216);         //  73728 B
    float* bbg      = (float*)(ws + 562944);         //    768 B

    kA<<<dim3(5, 32), 256, 0, stream>>>(xx, At_part);
    kB1<<<32, 256, 0, stream>>>(At_part, Acontrib);
    kB2<<<37, 256, 0, stream>>>(Acontrib, A_res, W, b, gamma, beta, rm, rv, bsTg, Wpg, bbg);
    kCf<<<dim3(15, 32), 384, 0, stream>>>(x, Wpg, bsTg, bbg, out);
}

// Round 21
// 153.984 us; speedup vs baseline: 1.5365x; 1.0294x over previous
//
#include <hip/hip_runtime.h>
#include <hip/hip_bf16.h>

typedef __attribute__((ext_vector_type(8))) short short8;
typedef __attribute__((ext_vector_type(4))) short short4v;
typedef __attribute__((ext_vector_type(4))) float f32x4;
typedef __attribute__((ext_vector_type(2))) float f32x2;

__device__ __forceinline__ unsigned short f2bf(float f) {
    unsigned int u = __builtin_bit_cast(unsigned int, f);
    u += 0x7fffu + ((u >> 16) & 1u);   // round-to-nearest-even
    return (unsigned short)(u >> 16);
}
__device__ __forceinline__ unsigned int pack2(float a, float b) {
    union { __hip_bfloat162 h; unsigned int u; } r;
    r.h = __float22bfloat162_rn(make_float2(a, b));
    return r.u;
}
__device__ __forceinline__ short4v cvt4(float a, float b, float c, float d) {
    union { __hip_bfloat162 h[2]; short4v s; } u;
    u.h[0] = __float22bfloat162_rn(make_float2(a, b));
    u.h[1] = __float22bfloat162_rn(make_float2(c, d));
    return u.s;
}

// ---------------------------------------------------------------------------
// Kernel A: partial adjacency sums over 60-frame chunks. grid (5,32).
// ---------------------------------------------------------------------------
__global__ void kA(const float* __restrict__ xx, float* __restrict__ At_part) {
    __shared__ float xs3[3][60][25];
    const int tc = blockIdx.x, n = blockIdx.y;
    const int tid = threadIdx.x;
    const float* base = xx + (size_t)n * 22500 + tc * 1500;
    for (int idx = tid; idx < 4500; idx += 256) {
        int ch = idx / 1500, rt = idx % 1500;
        xs3[ch][rt / 25][rt % 25] = base[ch * 7500 + rt];
    }
    __syncthreads();
    for (int p = tid; p < 625; p += 256) {
        int v = p / 25, u = p % 25;
        float s = 0.f;
        for (int t = 0; t < 60; ++t) {
            float dx = xs3[0][t][v] - xs3[0][t][u];
            float dy = xs3[1][t][v] - xs3[1][t][u];
            float dz = xs3[2][t][v] - xs3[2][t][u];
            s += __expf(-2.f * (dx * dx + dy * dy + dz * dz));
        }
        At_part[(size_t)(n * 5 + tc) * 625 + p] = s;
    }
}

// ---------------------------------------------------------------------------
// Kernel B1: per-sample reduce + symmetric normalization. grid 32.
// ---------------------------------------------------------------------------
__global__ void kB1(const float* __restrict__ At_part, float* __restrict__ Acontrib) {
    __shared__ float At[625];
    __shared__ float dinv[25];
    const int n = blockIdx.x, tid = threadIdx.x;
    for (int p = tid; p < 625; p += 256) {
        float s = 0.f;
        for (int tc = 0; tc < 5; ++tc) s += At_part[(size_t)(n * 5 + tc) * 625 + p];
        At[p] = s;
    }
    __syncthreads();
    if (tid < 25) {
        float d = 0.f;
        for (int u = 0; u < 25; ++u) d += At[tid * 25 + u];
        dinv[tid] = rsqrtf(d * (1.f / 300.f));
    }
    __syncthreads();
    for (int p = tid; p < 625; p += 256)
        Acontrib[n * 625 + p] = At[p] * (1.f / 300.f) * dinv[p / 25] * dinv[p % 25] * (1.f / 32.f);
}

// ---------------------------------------------------------------------------
// Kernel B2: block 0 -> bsTg (bf16 [64][72], zero-padded) + fused bias;
//            blocks 1..36 -> W'' = W * bn_scale  (layout [o][k], row-major).
// ---------------------------------------------------------------------------
__global__ void kB2(const float* __restrict__ Acontrib, const float* __restrict__ A_res,
                    const float* __restrict__ W, const float* __restrict__ b,
                    const float* __restrict__ gamma, const float* __restrict__ beta,
                    const float* __restrict__ rm, const float* __restrict__ rv,
                    short* __restrict__ bsTg, short* __restrict__ Wpg,
                    float* __restrict__ bbg) {
    const int tid = threadIdx.x;
    if (blockIdx.x == 0) {
        __shared__ float macc[625];
        for (int p = tid; p < 625; p += 256) {
            float s = 0.f;
            for (int n = 0; n < 32; ++n) s += Acontrib[n * 625 + p];
            macc[p] = s;
        }
        __syncthreads();
        for (int idx = tid; idx < 64 * 72; idx += 256) {
            int col = idx / 72, u = idx % 72;
            float v = 0.f;
            if (col < 50 && u < 50) v = macc[(col % 25) * 25 + (u % 25)] + A_res[col * 50 + u];
            bsTg[idx] = (short)f2bf(v);
        }
        if (tid < 192) {
            float sc = gamma[tid] * rsqrtf(rv[tid] + 1e-5f);
            bbg[tid] = b[tid] * sc + beta[tid] - rm[tid] * sc;
        }
    } else {
        const int e = (blockIdx.x - 1) * 1024 + tid * 4;
        const int o = e / 192;
        const float sc = gamma[o] * rsqrtf(rv[o] + 1e-5f);
        float4 w = *(const float4*)(W + e);
        short4v s4 = { (short)f2bf(w.x * sc), (short)f2bf(w.y * sc),
                       (short)f2bf(w.z * sc), (short)f2bf(w.w * sc) };
        *(short4v*)(Wpg + e) = s4;
    }
}

// ---------------------------------------------------------------------------
// Fused kernel kCf: graph-conv + 1x1 conv + BN + ReLU, no intermediate.
// grid (15,32)=480 blocks (~2/CU residency, ONE round), 384 thr = 6 waves,
// TC=20 timesteps/block, ONE lgkm+barrier per t (R20 structure).
// NEW vs R20: deferred paired stores -- even-t epilogue values are banked in
// registers (st[2][8]) and written together with odd-t's, so each (n,o) row
// receives its two adjacent 100B regions back-to-back (L2 sector merge;
// kills the 1.27x write amplification).
// ---------------------------------------------------------------------------
#define TCF 20
__global__ __launch_bounds__(384, 3)
void kCf(const float* __restrict__ x, const short* __restrict__ Wpg,
         const short* __restrict__ bsTg, const float* __restrict__ bbg,
         float* __restrict__ out) {
    __shared__ __align__(16) char xsb[2 * 12288];
    __shared__ __align__(16) short bsT[64 * 72];
    __shared__ __align__(16) short a2T[2][32][208];

    const int tid = threadIdx.x;
    const int lane = tid & 63;
    const int wid = tid >> 6;          // 0..5
    const int lam = lane & 15;
    const int kc = (lane >> 4) * 8;
    const int cb = (lane >> 4) * 4;
    const int n = blockIdx.y;
    const int t0 = blockIdx.x * TCF;
    const int gb0 = n * 1440000 + t0 * 50;
    const int cgl = wid * 16 + lam;

    // ---- t-invariant per-thread stage offsets ----
    int goff[7], loff[7];
#pragma unroll
    for (int i = 0; i < 7; ++i) {
        int idx = i * 384 + tid;
        int idc = idx < 2400 ? idx : 2399;
        int c = idc / 25, q = idc - c * 25;
        goff[i] = c * 15000 + 2 * q;
        loff[i] = (c * 128 + q * 4) ^ ((c & 7) << 4);
    }

    // W'' fragments in regs (GEMM2 B-operand) + bias
    short8 wf[2][6];
#pragma unroll
    for (int ot = 0; ot < 2; ++ot)
#pragma unroll
        for (int ks = 0; ks < 6; ++ks)
            wf[ot][ks] = *(const short8*)(Wpg + ((2 * wid + ot) * 16 + lam) * 192 + ks * 32 + kc);
    float bb[2];
#pragma unroll
    for (int ot = 0; ot < 2; ++ot) bb[ot] = bbg[(2 * wid + ot) * 16 + lam];

    // ---- prologue ----
    f32x2 pf2[13];
#pragma unroll
    for (int i = 0; i < 13; ++i) {
        int idx = i * 384 + tid;
        idx = idx < 4800 ? idx : 4799;
        int c = idx / 50, q2 = idx - c * 50;
        int tl = q2 >= 25, q = q2 - 25 * tl;
        pf2[i] = *(const f32x2*)(x + gb0 + c * 15000 + tl * 50 + 2 * q);
    }
    {
        const int4* src = (const int4*)bsTg;
        int4* dst = (int4*)bsT;
        for (int i = tid; i < 576; i += 384) dst[i] = src[i];
    }
    // zero xsb u-pads (both slots)
    for (int idx = tid; idx < 1344; idx += 384) {
        int r = idx / 7, k = idx - r * 7;
        int slot = r / 96, c = r - 96 * slot;
        *(unsigned int*)(xsb + ((slot * 12288 + c * 128 + (50 + 2 * k) * 2) ^ ((c & 7) << 4))) = 0;
    }
    // zero a2T pad rows 25..31 (both buffers)
    for (int idx = tid; idx < 1456; idx += 384) {
        int buf = idx / 728, rem = idx - buf * 728;
        int row = 25 + rem / 104, col2 = rem - (rem / 104) * 104;
        *((unsigned int*)&a2T[buf][row][0] + col2) = 0;
    }
    // write t0 -> slot0, t1 -> slot1
#pragma unroll
    for (int i = 0; i < 13; ++i) {
        int idx = i * 384 + tid;
        if (idx < 4800) {
            int c = idx / 50, q2 = idx - c * 50;
            int tl = q2 >= 25, q = q2 - 25 * tl;
            *(unsigned int*)(xsb + ((tl * 12288 + c * 128 + q * 4) ^ ((c & 7) << 4)))
                = pack2(pf2[i].x, pf2[i].y);
        }
    }
    asm volatile("s_waitcnt lgkmcnt(0)" ::: "memory");
    __builtin_amdgcn_s_barrier();

    const f32x4 z = {0.f, 0.f, 0.f, 0.f};
    f32x2 pf[7];
    float st[2][8];                     // banked even-t epilogue values

#pragma unroll 1
    for (int tl = 0; tl < TCF; ++tl) {
        const int slot = tl & 1;
        short* a2w = &a2T[slot][0][0];

        // issue t+2 coalesced loads early (precomputed addresses)
        if (tl < TCF - 2) {
            const float* xb2 = x + gb0 + (tl + 2) * 50;
#pragma unroll
            for (int i = 0; i < 7; ++i)
                if (i < 6 || tid < 96) pf[i] = *(const f32x2*)(xb2 + goff[i]);
        }

        // ---- GEMM1: D[v][c] (8 MFMA) ----
        short8 xb[2];
#pragma unroll
        for (int ks = 0; ks < 2; ++ks)
            xb[ks] = *(const short8*)(xsb +
                ((slot * 12288 + cgl * 128 + (ks * 32 + kc) * 2) ^ ((cgl & 7) << 4)));
        f32x4 acc1[4];
#pragma unroll
        for (int m = 0; m < 4; ++m) acc1[m] = z;
#pragma unroll
        for (int ks = 0; ks < 2; ++ks)
#pragma unroll
            for (int m = 0; m < 4; ++m) {
                const short8 af = *(const short8*)(bsT + (m * 16 + lam) * 72 + ks * 32 + kc);
                acc1[m] = __builtin_amdgcn_mfma_f32_16x16x32_bf16(af, xb[ks], acc1[m], 0, 0, 0);
            }

        // scatter agg -> a2T[slot][vs][s*96 + c]
#pragma unroll
        for (int m = 0; m < 3; ++m) {
            short4v sv = cvt4(acc1[m][0], acc1[m][1], acc1[m][2], acc1[m][3]);
#pragma unroll
            for (int r = 0; r < 4; ++r) {
                const int v = m * 16 + cb + r;
                const int s = v >= 25;
                a2w[(v - 25 * s) * 208 + s * 96 + cgl] = sv[r];
            }
        }
        if (cb == 0) {
            a2w[23 * 208 + 96 + cgl] = (short)f2bf(acc1[3][0]);
            a2w[24 * 208 + 96 + cgl] = (short)f2bf(acc1[3][1]);
        }
        asm volatile("s_waitcnt lgkmcnt(0)" ::: "memory");
        __builtin_amdgcn_s_barrier();   // a2T[slot] ready; all xb reads done

        // ---- GEMM2 (flipped): D[tv][o], W'' from registers (24 MFMA) ----
        f32x4 acc2[2][2];
#pragma unroll
        for (int g = 0; g < 2; ++g) { acc2[g][0] = z; acc2[g][1] = z; }
#pragma unroll
        for (int ks = 0; ks < 6; ++ks) {
            const short8 A0 = *(const short8*)(a2w + lam * 208 + ks * 32 + kc);
            const short8 A1 = *(const short8*)(a2w + (16 + lam) * 208 + ks * 32 + kc);
#pragma unroll
            for (int ot = 0; ot < 2; ++ot) {
                acc2[0][ot] = __builtin_amdgcn_mfma_f32_16x16x32_bf16(A0, wf[ot][ks], acc2[0][ot], 0, 0, 0);
                acc2[1][ot] = __builtin_amdgcn_mfma_f32_16x16x32_bf16(A1, wf[ot][ks], acc2[1][ot], 0, 0, 0);
            }
        }

        // ---- epilogue: defer even-t, store both t-1 and t on odd tl ----
        if ((tl & 1) == 0) {
#pragma unroll
            for (int ot = 0; ot < 2; ++ot) {
#pragma unroll
                for (int r = 0; r < 4; ++r) {
                    float vv = acc2[0][ot][r] + bb[ot];
                    st[ot][r] = vv > 0.f ? vv : 0.f;
                }
#pragma unroll
                for (int r = 0; r < 4; ++r) {
                    float vv = acc2[1][ot][r] + bb[ot];
                    st[ot][4 + r] = vv > 0.f ? vv : 0.f;
                }
            }
        } else {
            const int t = t0 + tl;
#pragma unroll
            for (int ot = 0; ot < 2; ++ot) {
                const int o = (2 * wid + ot) * 16 + lam;
                float* ope = out + ((size_t)(n * 192 + o) * 300 + (t - 1)) * 25;
                float* opo = ope + 25;
                // even-t region (banked)
#pragma unroll
                for (int r = 0; r < 4; ++r) ope[cb + r] = st[ot][r];
#pragma unroll
                for (int r = 0; r < 4; ++r) {
                    const int tv = 16 + cb + r;
                    if (tv < 25) ope[tv] = st[ot][4 + r];
                }
                // odd-t region (current)
#pragma unroll
                for (int r = 0; r < 4; ++r) {
                    float vv = acc2[0][ot][r] + bb[ot];
                    opo[cb + r] = vv > 0.f ? vv : 0.f;
                }
#pragma unroll
                for (int r = 0; r < 4; ++r) {
                    const int tv = 16 + cb + r;
                    if (tv < 25) {
                        float vv = acc2[1][ot][r] + bb[ot];
                        opo[tv] = vv > 0.f ? vv : 0.f;
                    }
                }
            }
        }

        // write t+2 into the freed slot
        if (tl < TCF - 2) {
            char* xw = xsb + slot * 12288;
#pragma unroll
            for (int i = 0; i < 7; ++i)
                if (i < 6 || tid < 96)
                    *(unsigned int*)(xw + loff[i]) = pack2(pf[i].x, pf[i].y);
        }
        // no trailing barrier: double-buffered xsb/a2T; next iter's
        // lgkm(0)+barrier orders these LDS writes before their reads.
    }
}

// ---------------------------------------------------------------------------
extern "C" void kernel_launch(void* const* d_in, const int* in_sizes, int n_in,
                              void* d_out, int out_size, void* d_ws, size_t ws_size,
                              hipStream_t stream) {
    const float* x     = (const float*)d_in[0];
    const float* xx    = (const float*)d_in[1];
    const float* A_res = (const float*)d_in[2];
    const float* W     = (const float*)d_in[3];
    const float* b     = (const float*)d_in[4];
    const float* gamma = (const float*)d_in[5];
    const float* beta  = (const float*)d_in[6];
    const float* rm    = (const float*)d_in[7];
    const float* rv    = (const float*)d_in[8];
    float* out = (float*)d_out;

    char* ws = (char*)d_ws;
    float* At_part  = (float*)ws;                    // 400000 B
    float* Acontrib = (float*)(ws + 400000);         //  80000 B
    short* bsTg     = (short*)(ws + 480000);         //   9216 B
    short* Wpg      = (short*)(ws + 489216);         //  73728 B
    float* bbg      = (float*)(ws + 562944);         //    768 B

    kA<<<dim3(5, 32), 256, 0, stream>>>(xx, At_part);
    kB1<<<32, 256, 0, stream>>>(At_part, Acontrib);
    kB2<<<37, 256, 0, stream>>>(Acontrib, A_res, W, b, gamma, beta, rm, rv, bsTg, Wpg, bbg);
    kCf<<<dim3(15, 32), 384, 0, stream>>>(x, Wpg, bsTg, bbg, out);
}